// Round 7
// baseline (286.507 us; speedup 1.0000x reference)
//
#include <hip/hip_runtime.h>
#include <cstddef>
#include <cstdint>

#define SQ    1023
#define HIDC  2048
#define NQC   10240
#define NKVC  1024

typedef unsigned short ushort_t;
typedef __bf16 bf16x8 __attribute__((ext_vector_type(8)));
typedef float  f32x4  __attribute__((ext_vector_type(4)));

__device__ __forceinline__ ushort_t f2bf(float x) {
  union { float f; uint32_t u; } v; v.f = x;
  uint32_t r = v.u + 0x7fffu + ((v.u >> 16) & 1u);   // RNE
  return (ushort_t)(r >> 16);
}

// native f32->bf16 (compiler emits packed cvt; RNE) — hot paths only
__device__ __forceinline__ ushort_t f2bf_fast(float x) {
  __bf16 b = (__bf16)x;
  return __builtin_bit_cast(ushort_t, b);
}

// ======================= RoPE tables =======================
__global__ void k_tables(float* __restrict__ cosT, float* __restrict__ sinT) {
  int idx = blockIdx.x * blockDim.x + threadIdx.x;
  if (idx >= SQ * 64) return;
  int t = idx >> 6, i = idx & 63;
  float inv = powf(10000.0f, -(float)i * (1.0f / 64.0f));
  float f = (float)t * inv;
  cosT[idx] = cosf(f);
  sinT[idx] = sinf(f);
}

// ======================= RoPE + scale + bf16 (Q) =======================
// NOTE: scale folds log2(e) so attention uses exp2 (S in log2 domain).
__global__ void k_rope_q(const float* __restrict__ q, ushort_t* __restrict__ qb,
                         const float* __restrict__ cosT, const float* __restrict__ sinT) {
  int idx = blockIdx.x * blockDim.x + threadIdx.x;
  if (idx >= 5115 * 16 * 64) return;
  int d  = idx & 63;
  int h  = (idx >> 6) & 15;
  int st = idx >> 10;            // g*1023 + t
  int t  = st % 1023;
  size_t base = (((size_t)st * 16) + h) * 128 + d;
  float x0 = q[base], x1 = q[base + 64];
  float c = cosT[t * 64 + d], s = sinT[t * 64 + d];
  const float sc = 0.1275174485f;   // log2(e) / sqrt(128)
  qb[base]      = f2bf((x0 * c - x1 * s) * sc);
  qb[base + 64] = f2bf((x1 * c + x0 * s) * sc);
}

// ======================= RoPE + bf16 (K), sums 4 split-K partials =======
__global__ void k_rope_k(const float* __restrict__ kvp, ushort_t* __restrict__ kb,
                         const float* __restrict__ cosT, const float* __restrict__ sinT) {
  int idx = blockIdx.x * blockDim.x + threadIdx.x;
  if (idx >= SQ * 4 * 64) return;
  int d   = idx & 63;
  int kvh = (idx >> 6) & 3;
  int t   = idx >> 8;
  size_t src = (size_t)t * 1024 + kvh * 128 + d;
  float x0 = 0.f, x1 = 0.f;
  #pragma unroll
  for (int z = 0; z < 4; ++z) {
    x0 += kvp[(size_t)z * (SQ * 1024) + src];
    x1 += kvp[(size_t)z * (SQ * 1024) + src + 64];
  }
  float c = cosT[t * 64 + d], s = sinT[t * 64 + d];
  size_t dst = (size_t)t * 512 + kvh * 128 + d;
  kb[dst]      = f2bf(x0 * c - x1 * s);
  kb[dst + 64] = f2bf(x1 * c + x0 * s);
}

// ======================= V transpose (sums 4 partials) =======================
__global__ __launch_bounds__(256)
void k_vtrans(const float* __restrict__ kvp, ushort_t* __restrict__ vt) {
  __shared__ float tile[32][33];
  int v0 = blockIdx.x * 32;
  int t0 = blockIdx.y * 32;
  int r = threadIdx.x >> 5, c = threadIdx.x & 31;
  #pragma unroll
  for (int p = 0; p < 4; ++p) {
    int t = t0 + p * 8 + r;
    float s = 0.f;
    if (t < SQ) {
      size_t src = (size_t)t * 1024 + 512 + v0 + c;
      #pragma unroll
      for (int z = 0; z < 4; ++z) s += kvp[(size_t)z * (SQ * 1024) + src];
    }
    tile[p * 8 + r][c] = s;
  }
  __syncthreads();
  #pragma unroll
  for (int p = 0; p < 4; ++p) {
    int v = v0 + p * 8 + r;
    vt[(size_t)v * 1024 + t0 + c] = f2bf(tile[c][p * 8 + r]);
  }
}

// ======================= f32 -> bf16 convert =======================
__global__ void k_f2b(const float* __restrict__ in, ushort_t* __restrict__ out, int n) {
  int i = (blockIdx.x * blockDim.x + threadIdx.x) * 4;
  if (i >= n) return;
  float4 v = *reinterpret_cast<const float4*>(in + i);
  uint2 pk;
  pk.x = (uint32_t)f2bf(v.x) | ((uint32_t)f2bf(v.y) << 16);
  pk.y = (uint32_t)f2bf(v.z) | ((uint32_t)f2bf(v.w) << 16);
  *reinterpret_cast<uint2*>(out + i) = pk;
}

// akv[r][c] = bf16( c<2048 ? prevh[r][c] : hidden[r][c-2048] )
__global__ void k_concat_b(const float* __restrict__ prevh, const float* __restrict__ hidden,
                           ushort_t* __restrict__ out) {
  int i = (blockIdx.x * blockDim.x + threadIdx.x) * 4;
  if (i >= SQ * 4096) return;
  int r = i >> 12, c = i & 4095;
  const float* src = (c < 2048) ? (prevh + (size_t)r * 2048 + c)
                                : (hidden + (size_t)r * 2048 + (c - 2048));
  float4 v = *reinterpret_cast<const float4*>(src);
  uint2 pk;
  pk.x = (uint32_t)f2bf(v.x) | ((uint32_t)f2bf(v.y) << 16);
  pk.y = (uint32_t)f2bf(v.z) | ((uint32_t)f2bf(v.w) << 16);
  *reinterpret_cast<uint2*>(out + (size_t)r * 4096 + c) = pk;
}

// ======================= transpose + convert: W [K][N] f32 -> Wt [N][K] bf16 ======
__global__ __launch_bounds__(256)
void k_tconv(const float* __restrict__ in, ushort_t* __restrict__ out, int K, int N) {
  __shared__ float t[32][33];
  int n0 = blockIdx.x * 32, k0 = blockIdx.y * 32;
  int r = threadIdx.x >> 5, c = threadIdx.x & 31;
  #pragma unroll
  for (int p = 0; p < 4; ++p)
    t[p * 8 + r][c] = in[(size_t)(k0 + p * 8 + r) * N + n0 + c];
  __syncthreads();
  #pragma unroll
  for (int p = 0; p < 4; ++p)
    out[(size_t)(n0 + p * 8 + r) * K + k0 + c] = f2bf(t[c][p * 8 + r]);
}

// == bf16 MFMA GEMM, 128x128 tile, BK=32, 3-buffer + counted vmcnt (T4) ========
// C[M][N] f32 = A[M][Kd] @ Bt[N][Kd] bf16. 4 waves (2x2), wave 64x64 (4x4 frags).
// Schedule/iter: waitcnt vmcnt(4) [drain oldest stage only] -> s_barrier ->
// STAGE(t+2) -> ds-read frags + 16 MFMA. One barrier per K-step; next stage's
// 4 loads stay in flight across it. Race-free: barrier is collective, so
// compute(t-1) is globally done before any wave overwrites buf (t+2)%3.
__global__ __launch_bounds__(256)
void k_gemm3buf(const ushort_t* __restrict__ A, const ushort_t* __restrict__ Bt,
                float* __restrict__ C, int M, int N, int Kd)
{
  __shared__ __align__(16) ushort_t As[3][128 * 32];
  __shared__ __align__(16) ushort_t Bs[3][128 * 32];

  const int tid  = threadIdx.x;
  const int lane = tid & 63;
  const int w    = tid >> 6;
  const int wm   = w >> 1, wn = w & 1;
  const int fr   = lane & 15;            // frag row (A) / col (B)
  const int kg   = (lane >> 4) * 8;      // frag k base
  const int m0   = blockIdx.y * 128, n0 = blockIdx.x * 128;

  const int lrow = lane >> 2;            // staging row within chunk
  const int lk   = (lane & 3) * 8;       // staging k elements

  f32x4 acc[4][4];
  #pragma unroll
  for (int i = 0; i < 4; ++i)
    #pragma unroll
    for (int j = 0; j < 4; ++j) acc[i][j] = (f32x4){0.f, 0.f, 0.f, 0.f};

  // STAGE: global -> LDS buffer b, K-offset k0 (2 A-loads + 2 B-loads / thread)
  auto STAGE = [&](int b, int k0) {
    #pragma unroll
    for (int c = 0; c < 2; ++c) {
      int ch  = w + c * 4;               // chunk 0..7 -> rows [ch*16, ch*16+16)
      int row = ch * 16 + lrow;
      const ushort_t* ga = A  + (size_t)(m0 + row) * Kd + k0 + lk;
      const ushort_t* gb = Bt + (size_t)(n0 + row) * Kd + k0 + lk;
      __builtin_amdgcn_global_load_lds(
          (const __attribute__((address_space(1))) void*)ga,
          (__attribute__((address_space(3))) void*)(&As[b][0] + ch * 512), 16, 0, 0);
      __builtin_amdgcn_global_load_lds(
          (const __attribute__((address_space(1))) void*)gb,
          (__attribute__((address_space(3))) void*)(&Bs[b][0] + ch * 512), 16, 0, 0);
    }
  };

  const int nt = Kd / 32;                // >= 2 always here (K = 2048)
  STAGE(0, 0);
  STAGE(1, 32);

  int cur = 0;
  for (int t = 0; t < nt; ++t) {
    if (t + 1 < nt) {
      asm volatile("s_waitcnt vmcnt(4)" ::: "memory");   // oldest stage done
    } else {
      asm volatile("s_waitcnt vmcnt(0)" ::: "memory");   // last tile: drain all
    }
    __builtin_amdgcn_s_barrier();
    if (t + 2 < nt) {
      int sb = cur + 2; if (sb >= 3) sb -= 3;
      STAGE(sb, (t + 2) * 32);
    }

    bf16x8 av[4], bv[4];
    #pragma unroll
    for (int mi = 0; mi < 4; ++mi)
      av[mi] = *reinterpret_cast<const bf16x8*>(&As[cur][0] + (wm * 64 + mi * 16 + fr) * 32 + kg);
    #pragma unroll
    for (int nj = 0; nj < 4; ++nj)
      bv[nj] = *reinterpret_cast<const bf16x8*>(&Bs[cur][0] + (wn * 64 + nj * 16 + fr) * 32 + kg);
    #pragma unroll
    for (int mi = 0; mi < 4; ++mi)
      #pragma unroll
      for (int nj = 0; nj < 4; ++nj)
        acc[mi][nj] = __builtin_amdgcn_mfma_f32_16x16x32_bf16(av[mi], bv[nj], acc[mi][nj], 0, 0, 0);

    cur = (cur == 2) ? 0 : cur + 1;
  }

  // C/D layout: col = lane&15, row = (lane>>4)*4 + r
  #pragma unroll
  for (int mi = 0; mi < 4; ++mi) {
    #pragma unroll
    for (int nj = 0; nj < 4; ++nj) {
      int rbase = m0 + wm * 64 + mi * 16 + (lane >> 4) * 4;
      int col   = n0 + wn * 64 + nj * 16 + fr;
      #pragma unroll
      for (int r = 0; r < 4; ++r) {
        int gr = rbase + r;
        if (gr < M) C[(size_t)gr * N + col] = acc[mi][nj][r];
      }
    }
  }
}

// ======================= bf16 MFMA GEMM, 64x128 tile (GEMM2 split-K) =========
__global__ __launch_bounds__(256)
void k_gemm64(const ushort_t* __restrict__ A, const ushort_t* __restrict__ Bt,
              float* __restrict__ C, int M, int N, int Kd, int kLen)
{
  __shared__ __align__(16) ushort_t As[64 * 32];
  __shared__ __align__(16) ushort_t Bs[128 * 32];

  const int tid  = threadIdx.x;
  const int lane = tid & 63;
  const int w    = tid >> 6;
  const int wm   = w >> 1, wn = w & 1;
  const int fr   = lane & 15;
  const int kg   = (lane >> 4) * 8;
  const int g4   = lane >> 4;
  const int l15  = lane & 15;
  const int m0   = blockIdx.y * 64, n0 = blockIdx.x * 128;
  const int kOff = blockIdx.z * kLen;
  C += (size_t)blockIdx.z * M * N;

  const int arow = tid >> 2, aslot = (tid & 3) * 8;

  f32x4 acc[2][4];
  #pragma unroll
  for (int i = 0; i < 2; ++i)
    #pragma unroll
    for (int j = 0; j < 4; ++j) acc[i][j] = (f32x4){0.f, 0.f, 0.f, 0.f};

  for (int k0 = kOff; k0 < kOff + kLen; k0 += 32) {
    {
      const ushort_t* ga = A + (size_t)(m0 + arow) * Kd + k0 + aslot;
      __builtin_amdgcn_global_load_lds(
          (const __attribute__((address_space(1))) void*)ga,
          (__attribute__((address_space(3))) void*)(As + w * 512), 16, 0, 0);
    }
    #pragma unroll
    for (int c = 0; c < 2; ++c) {
      int u = c * 256 + tid;
      const ushort_t* gb = Bt + (size_t)(n0 + (u >> 2)) * Kd + k0 + (u & 3) * 8;
      __builtin_amdgcn_global_load_lds(
          (const __attribute__((address_space(1))) void*)gb,
          (__attribute__((address_space(3))) void*)(Bs + (c * 256 + w * 64) * 8), 16, 0, 0);
    }
    __syncthreads();

    bf16x8 av[2], bv[4];
    #pragma unroll
    for (int mi = 0; mi < 2; ++mi)
      av[mi] = *reinterpret_cast<const bf16x8*>(As + (wm * 32 + mi * 16 + fr) * 32 + kg);
    #pragma unroll
    for (int nj = 0; nj < 4; ++nj)
      bv[nj] = *reinterpret_cast<const bf16x8*>(Bs + (wn * 64 + nj * 16 + fr) * 32 + kg);
    #pragma unroll
    for (int mi = 0; mi < 2; ++mi)
      #pragma unroll
      for (int nj = 0; nj < 4; ++nj)
        acc[mi][nj] = __builtin_amdgcn_mfma_f32_16x16x32_bf16(av[mi], bv[nj], acc[mi][nj], 0, 0, 0);
    __syncthreads();
  }

  #pragma unroll
  for (int mi = 0; mi < 2; ++mi) {
    #pragma unroll
    for (int nj = 0; nj < 4; ++nj) {
      int rbase = m0 + wm * 32 + mi * 16 + g4 * 4;
      int col   = n0 + wn * 64 + nj * 16 + l15;
      #pragma unroll
      for (int r = 0; r < 4; ++r) {
        int gr = rbase + r;
        if (gr < M) C[(size_t)gr * N + col] = acc[mi][nj][r];
      }
    }
  }
}

// ======================= MFMA flash attention (exp2 domain) ==================
// grid (80, 16): x = g*16+h, y -> qt = 15 - y (heavy first). 256 thr = 4 waves.
// Q pre-scaled by log2(e)/sqrt(128) -> S is in log2 domain; softmax uses exp2.
__global__ __launch_bounds__(256)
void k_attn_mfma(const ushort_t* __restrict__ qb, const ushort_t* __restrict__ kb,
                 const ushort_t* __restrict__ vt, ushort_t* __restrict__ oattb)
{
  __shared__ __align__(16) ushort_t Ks[64 * 128];   // [kv][128 d], slot s holds d-slot s^(kv&7)
  __shared__ __align__(16) ushort_t Vs[128 * 64];   // [d][64 kv], slot s holds kv-slot s^(d&7)
  __shared__ __align__(16) ushort_t Ps[4][16 * 64]; // per-wave P [16 q][64 kv], swizzled

  const int tid  = threadIdx.x;
  const int lane = tid & 63;
  const int w    = tid >> 6;
  const int l15  = lane & 15;
  const int g4   = lane >> 4;
  const int gh   = blockIdx.x;
  const int g = gh >> 4, h = gh & 15, kvh = (gh & 15) >> 2;
  const int qt = 15 - blockIdx.y;
  const int t0 = qt * 64;

  bf16x8 av[4];
  {
    int t = t0 + w * 16 + l15;
    const ushort_t* qrow = qb + (((size_t)(g * SQ + t)) * 16 + h) * 128;
    #pragma unroll
    for (int kk = 0; kk < 4; ++kk)
      av[kk] = *reinterpret_cast<const bf16x8*>(qrow + kk * 32 + g4 * 8);
  }

  f32x4 acc[8];
  #pragma unroll
  for (int dt = 0; dt < 8; ++dt) acc[dt] = (f32x4){0.f, 0.f, 0.f, 0.f};
  float m[4], l[4];
  #pragma unroll
  for (int r = 0; r < 4; ++r) { m[r] = -1e30f; l[r] = 0.f; }

  ushort_t* pw = &Ps[w][0];

  for (int jt = 0; jt <= qt; ++jt) {
    int u0 = jt * 64;
    #pragma unroll
    for (int i = 0; i < 4; ++i) {
      int c = (w * 4 + i) * 64 + lane;
      int kv = c >> 4, sl = c & 15;
      const ushort_t* srck = kb + (size_t)(u0 + kv) * 512 + kvh * 128 + ((sl ^ (kv & 7)) << 3);
      __builtin_amdgcn_global_load_lds(
          (const __attribute__((address_space(1))) void*)srck,
          (__attribute__((address_space(3))) void*)(Ks + (w * 4 + i) * 512), 16, 0, 0);
      int d = c >> 3, sv = c & 7;
      const ushort_t* srcv = vt + (size_t)(kvh * 128 + d) * 1024 + u0 + ((sv ^ (d & 7)) << 3);
      __builtin_amdgcn_global_load_lds(
          (const __attribute__((address_space(1))) void*)srcv,
          (__attribute__((address_space(3))) void*)(Vs + (w * 4 + i) * 512), 16, 0, 0);
    }
    __syncthreads();

    f32x4 S[4];
    #pragma unroll
    for (int ct = 0; ct < 4; ++ct) S[ct] = (f32x4){0.f, 0.f, 0.f, 0.f};
    #pragma unroll
    for (int ct = 0; ct < 4; ++ct) {
      int kv = ct * 16 + l15;
      #pragma unroll
      for (int kk = 0; kk < 4; ++kk) {
        bf16x8 bv = *reinterpret_cast<const bf16x8*>(
            Ks + kv * 128 + ((((kk << 2) | g4) ^ (kv & 7)) << 3));
        S[ct] = __builtin_amdgcn_mfma_f32_16x16x32_bf16(av[kk], bv, S[ct], 0, 0, 0);
      }
    }
    if (jt == qt) {
      #pragma unroll
      for (int ct = 0; ct < 4; ++ct) {
        int u = u0 + ct * 16 + l15;
        #pragma unroll
        for (int r = 0; r < 4; ++r) {
          int t = t0 + w * 16 + g4 * 4 + r;
          if (u > t) S[ct][r] = -1e30f;
        }
      }
    }
    // tile max per row
    float tm[4];
    #pragma unroll
    for (int r = 0; r < 4; ++r) {
      float t1 = fmaxf(fmaxf(S[0][r], S[1][r]), fmaxf(S[2][r], S[3][r]));
      t1 = fmaxf(t1, __shfl_xor(t1, 1));
      t1 = fmaxf(t1, __shfl_xor(t1, 2));
      t1 = fmaxf(t1, __shfl_xor(t1, 4));
      t1 = fmaxf(t1, __shfl_xor(t1, 8));
      tm[r] = t1;
    }
    // defer-max (T13): only rescale when some row grew past m + 8 (log2 units:
    // P bounded by 2^8 = 256 — safe for bf16 P and f32 l accum)
    bool need = (tm[0] > m[0] + 8.f) || (tm[1] > m[1] + 8.f) ||
                (tm[2] > m[2] + 8.f) || (tm[3] > m[3] + 8.f);
    if (__any(need)) {
      #pragma unroll
      for (int r = 0; r < 4; ++r) {
        float mn = fmaxf(m[r], tm[r]);
        float corr = exp2f(m[r] - mn);
        m[r] = mn;
        l[r] *= corr;
        #pragma unroll
        for (int dt = 0; dt < 8; ++dt) acc[dt][r] *= corr;
      }
    }
    #pragma unroll
    for (int r = 0; r < 4; ++r) {
      float ps = 0.f;
      #pragma unroll
      for (int ct = 0; ct < 4; ++ct) {
        float p = exp2f(S[ct][r] - m[r]);
        S[ct][r] = p;
        ps += p;
      }
      ps += __shfl_xor(ps, 1);
      ps += __shfl_xor(ps, 2);
      ps += __shfl_xor(ps, 4);
      ps += __shfl_xor(ps, 8);
      l[r] += ps;
    }

    #pragma unroll
    for (int ct = 0; ct < 4; ++ct) {
      int kv = ct * 16 + l15;
      #pragma unroll
      for (int r = 0; r < 4; ++r) {
        int q = g4 * 4 + r;
        pw[q * 64 + ((((kv >> 3) ^ (q & 7)) << 3) | (kv & 7))] = f2bf_fast(S[ct][r]);
      }
    }
    #pragma unroll
    for (int kk = 0; kk < 2; ++kk) {
      bf16x8 pa = *reinterpret_cast<const bf16x8*>(
          pw + l15 * 64 + ((((kk << 2) | g4) ^ (l15 & 7)) << 3));
      #pragma unroll
      for (int dt = 0; dt < 8; ++dt) {
        int d = dt * 16 + l15;
        bf16x8 vv = *reinterpret_cast<const bf16x8*>(
            Vs + d * 64 + ((((kk << 2) | g4) ^ (d & 7)) << 3));
        acc[dt] = __builtin_amdgcn_mfma_f32_16x16x32_bf16(pa, vv, acc[dt], 0, 0, 0);
      }
    }
    __syncthreads();
  }

  #pragma unroll
  for (int r = 0; r < 4; ++r) {
    int t = t0 + w * 16 + g4 * 4 + r;
    if (t >= SQ) continue;
    float inv = 1.f / l[r];
    ushort_t* dst = oattb + ((size_t)(g * SQ + t)) * 2048 + h * 128;
    #pragma unroll
    for (int dt = 0; dt < 8; ++dt)
      dst[dt * 16 + l15] = f2bf_fast(acc[dt][r] * inv);
  }
}

// ======================= launch =======================
extern "C" void kernel_launch(void* const* d_in, const int* in_sizes, int n_in,
                              void* d_out, int out_size, void* d_ws, size_t ws_size,
                              hipStream_t stream) {
  const float* hidden = (const float*)d_in[0];   // (1024, 2048)
  const float* prevh  = (const float*)d_in[1];   // (1023, 2048)
  const float* Wq     = (const float*)d_in[4];   // (2048, 10240)
  const float* Wkv    = (const float*)d_in[5];   // (4096, 1024)
  const float* Wo     = (const float*)d_in[6];   // (2048, 2048)
  float* out = (float*)d_out;                    // (5115, 2048)

  char* ws = (char*)d_ws;
  float*    kvp   = (float*)ws;                        ws += (size_t)4 * SQ * 1024 * 4;
  float*    cosT  = (float*)ws;                        ws += (size_t)65472 * 4;
  float*    sinT  = (float*)ws;                        ws += (size_t)65472 * 4;
  ushort_t* qbb   = (ushort_t*)ws;                     ws += (size_t)5120 * 2048 * 2;
  ushort_t* kb    = (ushort_t*)ws;                     ws += (size_t)1024 * 512 * 2;
  ushort_t* vtb   = (ushort_t*)ws;                     ws += (size_t)512 * 1024 * 2;
  ushort_t* hbf   = (ushort_t*)ws;                     ws += (size_t)1024 * 2048 * 2;
  ushort_t* akv   = (ushort_t*)ws;                     ws += (size_t)1024 * 4096 * 2;
  ushort_t* oattb = (ushort_t*)ws;                     ws += (size_t)5120 * 2048 * 2;
  ushort_t* wqt   = (ushort_t*)ws;                     ws += (size_t)10240 * 2048 * 2;
  ushort_t* wkvt  = (ushort_t*)ws;                     ws += (size_t)1024 * 4096 * 2;
  ushort_t* wot   = (ushort_t*)ws;                     ws += (size_t)2048 * 2048 * 2;

  float* qp = out;   // f32 q_proj scratch lives in d_out (1023*10240 elements, exact fit)

  k_tables<<<dim3((SQ * 64 + 255) / 256), dim3(256), 0, stream>>>(cosT, sinT);

  // weight transpose+convert
  k_tconv<<<dim3(NQC / 32, HIDC / 32), dim3(256), 0, stream>>>(Wq, wqt, HIDC, NQC);
  k_tconv<<<dim3(NKVC / 32, 4096 / 32), dim3(256), 0, stream>>>(Wkv, wkvt, 4096, NKVC);
  k_tconv<<<dim3(HIDC / 32, HIDC / 32), dim3(256), 0, stream>>>(Wo, wot, HIDC, HIDC);

  // A-matrix converts
  k_f2b<<<dim3((SQ * 2048 / 4 + 255) / 256), dim3(256), 0, stream>>>(hidden + 2048, hbf, SQ * 2048);
  k_concat_b<<<dim3((SQ * 4096 / 4 + 255) / 256), dim3(256), 0, stream>>>(prevh, hidden, akv);

  // q_proj = hidden[1:] @ Wq   (3-buffer counted-vmcnt, 640 blocks)
  k_gemm3buf<<<dim3(NQC / 128, 8), dim3(256), 0, stream>>>(hbf, wqt, qp, SQ, NQC, 2048);
  // kv = concat(prev,hidden) @ Wkv, split-K x4 (512 blocks)
  k_gemm64<<<dim3(NKVC / 128, 16, 4), dim3(256), 0, stream>>>(akv, wkvt, kvp, SQ, NKVC, 4096, 1024);

  // rope + bf16 pack (rope_k / vtrans fold the 4 kv partials)
  k_rope_q<<<dim3((5115 * 16 * 64 + 255) / 256), dim3(256), 0, stream>>>(qp, qbb, cosT, sinT);
  k_rope_k<<<dim3((SQ * 4 * 64 + 255) / 256), dim3(256), 0, stream>>>(kvp, kb, cosT, sinT);
  k_vtrans<<<dim3(16, 32), dim3(256), 0, stream>>>(kvp, vtb);

  // MFMA flash attention -> bf16 O
  k_attn_mfma<<<dim3(80, 16), dim3(256), 0, stream>>>(qbb, kb, vtb, oattb);

  // out = O_att @ Wo   (3-buffer counted-vmcnt, 640 blocks)
  k_gemm3buf<<<dim3(HIDC / 128, 40), dim3(256), 0, stream>>>(oattb, wot, out, 5115, HIDC, 2048);
}

// Round 8
// 279.821 us; speedup vs baseline: 1.0239x; 1.0239x over previous
//
#include <hip/hip_runtime.h>
#include <cstddef>
#include <cstdint>

#define SQ    1023
#define HIDC  2048
#define NQC   10240
#define NKVC  1024

typedef unsigned short ushort_t;
typedef __bf16 bf16x8 __attribute__((ext_vector_type(8)));
typedef float  f32x4  __attribute__((ext_vector_type(4)));

__device__ __forceinline__ ushort_t f2bf(float x) {
  union { float f; uint32_t u; } v; v.f = x;
  uint32_t r = v.u + 0x7fffu + ((v.u >> 16) & 1u);   // RNE
  return (ushort_t)(r >> 16);
}

// native f32->bf16 (compiler emits packed cvt; RNE) — hot paths only
__device__ __forceinline__ ushort_t f2bf_fast(float x) {
  __bf16 b = (__bf16)x;
  return __builtin_bit_cast(ushort_t, b);
}

// raw v_exp_f32 (computes 2^x). s_nop covers the TRANS-result wait state,
// which the compiler can't insert around opaque inline asm.
__device__ __forceinline__ float fexp2(float x) {
  float r;
  asm("v_exp_f32 %0, %1\n\ts_nop 0" : "=v"(r) : "v"(x));
  return r;
}

// ======================= RoPE tables =======================
__global__ void k_tables(float* __restrict__ cosT, float* __restrict__ sinT) {
  int idx = blockIdx.x * blockDim.x + threadIdx.x;
  if (idx >= SQ * 64) return;
  int t = idx >> 6, i = idx & 63;
  float inv = powf(10000.0f, -(float)i * (1.0f / 64.0f));
  float f = (float)t * inv;
  cosT[idx] = cosf(f);
  sinT[idx] = sinf(f);
}

// ======================= RoPE + bf16 (K), sums 4 split-K partials =======
__global__ void k_rope_k(const float* __restrict__ kvp, ushort_t* __restrict__ kb,
                         const float* __restrict__ cosT, const float* __restrict__ sinT) {
  int idx = blockIdx.x * blockDim.x + threadIdx.x;
  if (idx >= SQ * 4 * 64) return;
  int d   = idx & 63;
  int kvh = (idx >> 6) & 3;
  int t   = idx >> 8;
  size_t src = (size_t)t * 1024 + kvh * 128 + d;
  float x0 = 0.f, x1 = 0.f;
  #pragma unroll
  for (int z = 0; z < 4; ++z) {
    x0 += kvp[(size_t)z * (SQ * 1024) + src];
    x1 += kvp[(size_t)z * (SQ * 1024) + src + 64];
  }
  float c = cosT[t * 64 + d], s = sinT[t * 64 + d];
  size_t dst = (size_t)t * 512 + kvh * 128 + d;
  kb[dst]      = f2bf(x0 * c - x1 * s);
  kb[dst + 64] = f2bf(x1 * c + x0 * s);
}

// ======================= V transpose (sums 4 partials) =======================
__global__ __launch_bounds__(256)
void k_vtrans(const float* __restrict__ kvp, ushort_t* __restrict__ vt) {
  __shared__ float tile[32][33];
  int v0 = blockIdx.x * 32;
  int t0 = blockIdx.y * 32;
  int r = threadIdx.x >> 5, c = threadIdx.x & 31;
  #pragma unroll
  for (int p = 0; p < 4; ++p) {
    int t = t0 + p * 8 + r;
    float s = 0.f;
    if (t < SQ) {
      size_t src = (size_t)t * 1024 + 512 + v0 + c;
      #pragma unroll
      for (int z = 0; z < 4; ++z) s += kvp[(size_t)z * (SQ * 1024) + src];
    }
    tile[p * 8 + r][c] = s;
  }
  __syncthreads();
  #pragma unroll
  for (int p = 0; p < 4; ++p) {
    int v = v0 + p * 8 + r;
    vt[(size_t)v * 1024 + t0 + c] = f2bf(tile[c][p * 8 + r]);
  }
}

// ======================= f32 -> bf16 convert =======================
__global__ void k_f2b(const float* __restrict__ in, ushort_t* __restrict__ out, int n) {
  int i = (blockIdx.x * blockDim.x + threadIdx.x) * 4;
  if (i >= n) return;
  float4 v = *reinterpret_cast<const float4*>(in + i);
  uint2 pk;
  pk.x = (uint32_t)f2bf(v.x) | ((uint32_t)f2bf(v.y) << 16);
  pk.y = (uint32_t)f2bf(v.z) | ((uint32_t)f2bf(v.w) << 16);
  *reinterpret_cast<uint2*>(out + i) = pk;
}

// akv[r][c] = bf16( c<2048 ? prevh[r][c] : hidden[r][c-2048] )
__global__ void k_concat_b(const float* __restrict__ prevh, const float* __restrict__ hidden,
                           ushort_t* __restrict__ out) {
  int i = (blockIdx.x * blockDim.x + threadIdx.x) * 4;
  if (i >= SQ * 4096) return;
  int r = i >> 12, c = i & 4095;
  const float* src = (c < 2048) ? (prevh + (size_t)r * 2048 + c)
                                : (hidden + (size_t)r * 2048 + (c - 2048));
  float4 v = *reinterpret_cast<const float4*>(src);
  uint2 pk;
  pk.x = (uint32_t)f2bf(v.x) | ((uint32_t)f2bf(v.y) << 16);
  pk.y = (uint32_t)f2bf(v.z) | ((uint32_t)f2bf(v.w) << 16);
  *reinterpret_cast<uint2*>(out + (size_t)r * 4096 + c) = pk;
}

// ======================= transpose + convert: W [K][N] f32 -> Wt [N][K] bf16 ======
__global__ __launch_bounds__(256)
void k_tconv(const float* __restrict__ in, ushort_t* __restrict__ out, int K, int N) {
  __shared__ float t[32][33];
  int n0 = blockIdx.x * 32, k0 = blockIdx.y * 32;
  int r = threadIdx.x >> 5, c = threadIdx.x & 31;
  #pragma unroll
  for (int p = 0; p < 4; ++p)
    t[p * 8 + r][c] = in[(size_t)(k0 + p * 8 + r) * N + n0 + c];
  __syncthreads();
  #pragma unroll
  for (int p = 0; p < 4; ++p)
    out[(size_t)(n0 + p * 8 + r) * K + k0 + c] = f2bf(t[c][p * 8 + r]);
}

// == GEMM1 + fused RoPE: qbb = rope(hidden[1:] @ Wq) * log2e/sqrt(128), bf16 ===
// 128x128 tile, BK=32, 3-buffer counted-vmcnt. Wave cols REMAPPED so d and d+64
// of the same head live in the same wave/lane: colOff(nj) = wn*32+(nj&1)*16+(nj>>1)*64.
// Then acc[mi][njp] (d) pairs with acc[mi][njp+2] (d+64) in-register.
__global__ __launch_bounds__(256)
void k_gemm_rope(const ushort_t* __restrict__ A, const ushort_t* __restrict__ Bt,
                 ushort_t* __restrict__ Q, const float* __restrict__ cosT,
                 const float* __restrict__ sinT)
{
  const int Kd = 2048, N = NQC;
  __shared__ __align__(16) ushort_t As[3][128 * 32];
  __shared__ __align__(16) ushort_t Bs[3][128 * 32];

  const int tid  = threadIdx.x;
  const int lane = tid & 63;
  const int w    = tid >> 6;
  const int wm   = w >> 1, wn = w & 1;
  const int fr   = lane & 15;
  const int kg   = (lane >> 4) * 8;
  const int g4   = lane >> 4;
  const int m0   = blockIdx.y * 128, n0 = blockIdx.x * 128;

  const int lrow = lane >> 2;
  const int lk   = (lane & 3) * 8;

  f32x4 acc[4][4];
  #pragma unroll
  for (int i = 0; i < 4; ++i)
    #pragma unroll
    for (int j = 0; j < 4; ++j) acc[i][j] = (f32x4){0.f, 0.f, 0.f, 0.f};

  auto STAGE = [&](int b, int k0) {
    #pragma unroll
    for (int c = 0; c < 2; ++c) {
      int ch  = w + c * 4;
      int row = ch * 16 + lrow;
      const ushort_t* ga = A  + (size_t)(m0 + row) * Kd + k0 + lk;
      const ushort_t* gb = Bt + (size_t)(n0 + row) * Kd + k0 + lk;
      __builtin_amdgcn_global_load_lds(
          (const __attribute__((address_space(1))) void*)ga,
          (__attribute__((address_space(3))) void*)(&As[b][0] + ch * 512), 16, 0, 0);
      __builtin_amdgcn_global_load_lds(
          (const __attribute__((address_space(1))) void*)gb,
          (__attribute__((address_space(3))) void*)(&Bs[b][0] + ch * 512), 16, 0, 0);
    }
  };

  const int nt = Kd / 32;
  STAGE(0, 0);
  STAGE(1, 32);

  int cur = 0;
  for (int t = 0; t < nt; ++t) {
    if (t + 1 < nt) {
      asm volatile("s_waitcnt vmcnt(4)" ::: "memory");
    } else {
      asm volatile("s_waitcnt vmcnt(0)" ::: "memory");
    }
    __builtin_amdgcn_s_barrier();
    if (t + 2 < nt) {
      int sb = cur + 2; if (sb >= 3) sb -= 3;
      STAGE(sb, (t + 2) * 32);
    }

    bf16x8 av[4], bv[4];
    #pragma unroll
    for (int mi = 0; mi < 4; ++mi)
      av[mi] = *reinterpret_cast<const bf16x8*>(&As[cur][0] + (wm * 64 + mi * 16 + fr) * 32 + kg);
    #pragma unroll
    for (int nj = 0; nj < 4; ++nj) {
      int colOff = wn * 32 + (nj & 1) * 16 + (nj >> 1) * 64;   // remapped
      bv[nj] = *reinterpret_cast<const bf16x8*>(&Bs[cur][0] + (colOff + fr) * 32 + kg);
    }
    #pragma unroll
    for (int mi = 0; mi < 4; ++mi)
      #pragma unroll
      for (int nj = 0; nj < 4; ++nj)
        acc[mi][nj] = __builtin_amdgcn_mfma_f32_16x16x32_bf16(av[mi], bv[nj], acc[mi][nj], 0, 0, 0);

    cur = (cur == 2) ? 0 : cur + 1;
  }

  // fused RoPE epilogue. col = n0 + dd (+64), dd = wn*32 + njp*16 + fr in [0,64)
  // st = row*5 + n0/2048 (uniform per row in tile), tau = st % 1023.
  const float sc = 0.1275174485f;   // log2(e) / sqrt(128)
  const int nChunk = n0 >> 11;
  #pragma unroll
  for (int mi = 0; mi < 4; ++mi) {
    #pragma unroll
    for (int r = 0; r < 4; ++r) {
      int gr = m0 + wm * 64 + mi * 16 + g4 * 4 + r;
      if (gr >= SQ) continue;
      int st  = gr * 5 + nChunk;
      int tau = st % 1023;
      const float* ct = cosT + tau * 64;
      const float* stb = sinT + tau * 64;
      #pragma unroll
      for (int njp = 0; njp < 2; ++njp) {
        int dd = wn * 32 + njp * 16 + fr;
        float c = ct[dd], s = stb[dd];
        float x0 = acc[mi][njp][r];
        float x1 = acc[mi][njp + 2][r];
        size_t base = (size_t)gr * 10240 + n0 + dd;
        Q[base]      = f2bf_fast((x0 * c - x1 * s) * sc);
        Q[base + 64] = f2bf_fast((x1 * c + x0 * s) * sc);
      }
    }
  }
}

// == bf16 MFMA GEMM, 128x128 tile, BK=32, 3-buffer + counted vmcnt (GEMM3) ====
__global__ __launch_bounds__(256)
void k_gemm3buf(const ushort_t* __restrict__ A, const ushort_t* __restrict__ Bt,
                float* __restrict__ C, int M, int N, int Kd)
{
  __shared__ __align__(16) ushort_t As[3][128 * 32];
  __shared__ __align__(16) ushort_t Bs[3][128 * 32];

  const int tid  = threadIdx.x;
  const int lane = tid & 63;
  const int w    = tid >> 6;
  const int wm   = w >> 1, wn = w & 1;
  const int fr   = lane & 15;
  const int kg   = (lane >> 4) * 8;
  const int m0   = blockIdx.y * 128, n0 = blockIdx.x * 128;

  const int lrow = lane >> 2;
  const int lk   = (lane & 3) * 8;

  f32x4 acc[4][4];
  #pragma unroll
  for (int i = 0; i < 4; ++i)
    #pragma unroll
    for (int j = 0; j < 4; ++j) acc[i][j] = (f32x4){0.f, 0.f, 0.f, 0.f};

  auto STAGE = [&](int b, int k0) {
    #pragma unroll
    for (int c = 0; c < 2; ++c) {
      int ch  = w + c * 4;
      int row = ch * 16 + lrow;
      const ushort_t* ga = A  + (size_t)(m0 + row) * Kd + k0 + lk;
      const ushort_t* gb = Bt + (size_t)(n0 + row) * Kd + k0 + lk;
      __builtin_amdgcn_global_load_lds(
          (const __attribute__((address_space(1))) void*)ga,
          (__attribute__((address_space(3))) void*)(&As[b][0] + ch * 512), 16, 0, 0);
      __builtin_amdgcn_global_load_lds(
          (const __attribute__((address_space(1))) void*)gb,
          (__attribute__((address_space(3))) void*)(&Bs[b][0] + ch * 512), 16, 0, 0);
    }
  };

  const int nt = Kd / 32;
  STAGE(0, 0);
  STAGE(1, 32);

  int cur = 0;
  for (int t = 0; t < nt; ++t) {
    if (t + 1 < nt) {
      asm volatile("s_waitcnt vmcnt(4)" ::: "memory");
    } else {
      asm volatile("s_waitcnt vmcnt(0)" ::: "memory");
    }
    __builtin_amdgcn_s_barrier();
    if (t + 2 < nt) {
      int sb = cur + 2; if (sb >= 3) sb -= 3;
      STAGE(sb, (t + 2) * 32);
    }

    bf16x8 av[4], bv[4];
    #pragma unroll
    for (int mi = 0; mi < 4; ++mi)
      av[mi] = *reinterpret_cast<const bf16x8*>(&As[cur][0] + (wm * 64 + mi * 16 + fr) * 32 + kg);
    #pragma unroll
    for (int nj = 0; nj < 4; ++nj)
      bv[nj] = *reinterpret_cast<const bf16x8*>(&Bs[cur][0] + (wn * 64 + nj * 16 + fr) * 32 + kg);
    #pragma unroll
    for (int mi = 0; mi < 4; ++mi)
      #pragma unroll
      for (int nj = 0; nj < 4; ++nj)
        acc[mi][nj] = __builtin_amdgcn_mfma_f32_16x16x32_bf16(av[mi], bv[nj], acc[mi][nj], 0, 0, 0);

    cur = (cur == 2) ? 0 : cur + 1;
  }

  #pragma unroll
  for (int mi = 0; mi < 4; ++mi) {
    #pragma unroll
    for (int nj = 0; nj < 4; ++nj) {
      int rbase = m0 + wm * 64 + mi * 16 + (lane >> 4) * 4;
      int col   = n0 + wn * 64 + nj * 16 + fr;
      #pragma unroll
      for (int r = 0; r < 4; ++r) {
        int gr = rbase + r;
        if (gr < M) C[(size_t)gr * N + col] = acc[mi][nj][r];
      }
    }
  }
}

// ======================= bf16 MFMA GEMM, 64x128 tile (GEMM2 split-K) =========
__global__ __launch_bounds__(256)
void k_gemm64(const ushort_t* __restrict__ A, const ushort_t* __restrict__ Bt,
              float* __restrict__ C, int M, int N, int Kd, int kLen)
{
  __shared__ __align__(16) ushort_t As[64 * 32];
  __shared__ __align__(16) ushort_t Bs[128 * 32];

  const int tid  = threadIdx.x;
  const int lane = tid & 63;
  const int w    = tid >> 6;
  const int wm   = w >> 1, wn = w & 1;
  const int fr   = lane & 15;
  const int kg   = (lane >> 4) * 8;
  const int g4   = lane >> 4;
  const int l15  = lane & 15;
  const int m0   = blockIdx.y * 64, n0 = blockIdx.x * 128;
  const int kOff = blockIdx.z * kLen;
  C += (size_t)blockIdx.z * M * N;

  const int arow = tid >> 2, aslot = (tid & 3) * 8;

  f32x4 acc[2][4];
  #pragma unroll
  for (int i = 0; i < 2; ++i)
    #pragma unroll
    for (int j = 0; j < 4; ++j) acc[i][j] = (f32x4){0.f, 0.f, 0.f, 0.f};

  for (int k0 = kOff; k0 < kOff + kLen; k0 += 32) {
    {
      const ushort_t* ga = A + (size_t)(m0 + arow) * Kd + k0 + aslot;
      __builtin_amdgcn_global_load_lds(
          (const __attribute__((address_space(1))) void*)ga,
          (__attribute__((address_space(3))) void*)(As + w * 512), 16, 0, 0);
    }
    #pragma unroll
    for (int c = 0; c < 2; ++c) {
      int u = c * 256 + tid;
      const ushort_t* gb = Bt + (size_t)(n0 + (u >> 2)) * Kd + k0 + (u & 3) * 8;
      __builtin_amdgcn_global_load_lds(
          (const __attribute__((address_space(1))) void*)gb,
          (__attribute__((address_space(3))) void*)(Bs + (c * 256 + w * 64) * 8), 16, 0, 0);
    }
    __syncthreads();

    bf16x8 av[2], bv[4];
    #pragma unroll
    for (int mi = 0; mi < 2; ++mi)
      av[mi] = *reinterpret_cast<const bf16x8*>(As + (wm * 32 + mi * 16 + fr) * 32 + kg);
    #pragma unroll
    for (int nj = 0; nj < 4; ++nj)
      bv[nj] = *reinterpret_cast<const bf16x8*>(Bs + (wn * 64 + nj * 16 + fr) * 32 + kg);
    #pragma unroll
    for (int mi = 0; mi < 2; ++mi)
      #pragma unroll
      for (int nj = 0; nj < 4; ++nj)
        acc[mi][nj] = __builtin_amdgcn_mfma_f32_16x16x32_bf16(av[mi], bv[nj], acc[mi][nj], 0, 0, 0);
    __syncthreads();
  }

  #pragma unroll
  for (int mi = 0; mi < 2; ++mi) {
    #pragma unroll
    for (int nj = 0; nj < 4; ++nj) {
      int rbase = m0 + wm * 32 + mi * 16 + g4 * 4;
      int col   = n0 + wn * 64 + nj * 16 + l15;
      #pragma unroll
      for (int r = 0; r < 4; ++r) {
        int gr = rbase + r;
        if (gr < M) C[(size_t)gr * N + col] = acc[mi][nj][r];
      }
    }
  }
}

// ======================= MFMA flash attention (exp2 domain) ==================
// grid (80, 16): x = g*16+h, y -> qt = 15 - y (heavy first). 256 thr = 4 waves.
// Q pre-scaled by log2(e)/sqrt(128) -> S is in log2 domain; softmax uses v_exp.
__global__ __launch_bounds__(256)
void k_attn_mfma(const ushort_t* __restrict__ qb, const ushort_t* __restrict__ kb,
                 const ushort_t* __restrict__ vt, ushort_t* __restrict__ oattb)
{
  __shared__ __align__(16) ushort_t Ks[64 * 128];   // [kv][128 d], slot s holds d-slot s^(kv&7)
  __shared__ __align__(16) ushort_t Vs[128 * 64];   // [d][64 kv], slot s holds kv-slot s^(d&7)
  __shared__ __align__(16) ushort_t Ps[4][16 * 64]; // per-wave P [16 q][64 kv], swizzled

  const int tid  = threadIdx.x;
  const int lane = tid & 63;
  const int w    = tid >> 6;
  const int l15  = lane & 15;
  const int g4   = lane >> 4;
  const int gh   = blockIdx.x;
  const int g = gh >> 4, h = gh & 15, kvh = (gh & 15) >> 2;
  const int qt = 15 - blockIdx.y;
  const int t0 = qt * 64;

  bf16x8 av[4];
  {
    int t = t0 + w * 16 + l15;
    const ushort_t* qrow = qb + (((size_t)(g * SQ + t)) * 16 + h) * 128;
    #pragma unroll
    for (int kk = 0; kk < 4; ++kk)
      av[kk] = *reinterpret_cast<const bf16x8*>(qrow + kk * 32 + g4 * 8);
  }

  f32x4 acc[8];
  #pragma unroll
  for (int dt = 0; dt < 8; ++dt) acc[dt] = (f32x4){0.f, 0.f, 0.f, 0.f};
  float m[4], l[4];
  #pragma unroll
  for (int r = 0; r < 4; ++r) { m[r] = -1e30f; l[r] = 0.f; }

  ushort_t* pw = &Ps[w][0];

  for (int jt = 0; jt <= qt; ++jt) {
    int u0 = jt * 64;
    #pragma unroll
    for (int i = 0; i < 4; ++i) {
      int c = (w * 4 + i) * 64 + lane;
      int kv = c >> 4, sl = c & 15;
      const ushort_t* srck = kb + (size_t)(u0 + kv) * 512 + kvh * 128 + ((sl ^ (kv & 7)) << 3);
      __builtin_amdgcn_global_load_lds(
          (const __attribute__((address_space(1))) void*)srck,
          (__attribute__((address_space(3))) void*)(Ks + (w * 4 + i) * 512), 16, 0, 0);
      int d = c >> 3, sv = c & 7;
      const ushort_t* srcv = vt + (size_t)(kvh * 128 + d) * 1024 + u0 + ((sv ^ (d & 7)) << 3);
      __builtin_amdgcn_global_load_lds(
          (const __attribute__((address_space(1))) void*)srcv,
          (__attribute__((address_space(3))) void*)(Vs + (w * 4 + i) * 512), 16, 0, 0);
    }
    __syncthreads();

    f32x4 S[4];
    #pragma unroll
    for (int ct = 0; ct < 4; ++ct) S[ct] = (f32x4){0.f, 0.f, 0.f, 0.f};
    #pragma unroll
    for (int ct = 0; ct < 4; ++ct) {
      int kv = ct * 16 + l15;
      #pragma unroll
      for (int kk = 0; kk < 4; ++kk) {
        bf16x8 bv = *reinterpret_cast<const bf16x8*>(
            Ks + kv * 128 + ((((kk << 2) | g4) ^ (kv & 7)) << 3));
        S[ct] = __builtin_amdgcn_mfma_f32_16x16x32_bf16(av[kk], bv, S[ct], 0, 0, 0);
      }
    }
    if (jt == qt) {
      #pragma unroll
      for (int ct = 0; ct < 4; ++ct) {
        int u = u0 + ct * 16 + l15;
        #pragma unroll
        for (int r = 0; r < 4; ++r) {
          int t = t0 + w * 16 + g4 * 4 + r;
          if (u > t) S[ct][r] = -1e30f;
        }
      }
    }
    // tile max per row
    float tm[4];
    #pragma unroll
    for (int r = 0; r < 4; ++r) {
      float t1 = fmaxf(fmaxf(S[0][r], S[1][r]), fmaxf(S[2][r], S[3][r]));
      t1 = fmaxf(t1, __shfl_xor(t1, 1));
      t1 = fmaxf(t1, __shfl_xor(t1, 2));
      t1 = fmaxf(t1, __shfl_xor(t1, 4));
      t1 = fmaxf(t1, __shfl_xor(t1, 8));
      tm[r] = t1;
    }
    // defer-max (T13): only rescale when some row grew past m + 8 (log2 units:
    // P bounded by 2^8 = 256 — safe for bf16 P and f32 l accum)
    bool need = (tm[0] > m[0] + 8.f) || (tm[1] > m[1] + 8.f) ||
                (tm[2] > m[2] + 8.f) || (tm[3] > m[3] + 8.f);
    if (__any(need)) {
      #pragma unroll
      for (int r = 0; r < 4; ++r) {
        float mn = fmaxf(m[r], tm[r]);
        float corr = fexp2(m[r] - mn);
        m[r] = mn;
        l[r] *= corr;
        #pragma unroll
        for (int dt = 0; dt < 8; ++dt) acc[dt][r] *= corr;
      }
    }
    #pragma unroll
    for (int r = 0; r < 4; ++r) {
      float ps = 0.f;
      #pragma unroll
      for (int ct = 0; ct < 4; ++ct) {
        float p = fexp2(S[ct][r] - m[r]);
        S[ct][r] = p;
        ps += p;
      }
      ps += __shfl_xor(ps, 1);
      ps += __shfl_xor(ps, 2);
      ps += __shfl_xor(ps, 4);
      ps += __shfl_xor(ps, 8);
      l[r] += ps;
    }

    #pragma unroll
    for (int ct = 0; ct < 4; ++ct) {
      int kv = ct * 16 + l15;
      #pragma unroll
      for (int r = 0; r < 4; ++r) {
        int q = g4 * 4 + r;
        pw[q * 64 + ((((kv >> 3) ^ (q & 7)) << 3) | (kv & 7))] = f2bf_fast(S[ct][r]);
      }
    }
    #pragma unroll
    for (int kk = 0; kk < 2; ++kk) {
      bf16x8 pa = *reinterpret_cast<const bf16x8*>(
          pw + l15 * 64 + ((((kk << 2) | g4) ^ (l15 & 7)) << 3));
      #pragma unroll
      for (int dt = 0; dt < 8; ++dt) {
        int d = dt * 16 + l15;
        bf16x8 vv = *reinterpret_cast<const bf16x8*>(
            Vs + d * 64 + ((((kk << 2) | g4) ^ (d & 7)) << 3));
        acc[dt] = __builtin_amdgcn_mfma_f32_16x16x32_bf16(pa, vv, acc[dt], 0, 0, 0);
      }
    }
    __syncthreads();
  }

  #pragma unroll
  for (int r = 0; r < 4; ++r) {
    int t = t0 + w * 16 + g4 * 4 + r;
    if (t >= SQ) continue;
    float inv = 1.f / l[r];
    ushort_t* dst = oattb + ((size_t)(g * SQ + t)) * 2048 + h * 128;
    #pragma unroll
    for (int dt = 0; dt < 8; ++dt)
      dst[dt * 16 + l15] = f2bf_fast(acc[dt][r] * inv);
  }
}

// ======================= launch =======================
extern "C" void kernel_launch(void* const* d_in, const int* in_sizes, int n_in,
                              void* d_out, int out_size, void* d_ws, size_t ws_size,
                              hipStream_t stream) {
  const float* hidden = (const float*)d_in[0];   // (1024, 2048)
  const float* prevh  = (const float*)d_in[1];   // (1023, 2048)
  const float* Wq     = (const float*)d_in[4];   // (2048, 10240)
  const float* Wkv    = (const float*)d_in[5];   // (4096, 1024)
  const float* Wo     = (const float*)d_in[6];   // (2048, 2048)
  float* out = (float*)d_out;                    // (5115, 2048)

  char* ws = (char*)d_ws;
  float*    kvp   = (float*)ws;                        ws += (size_t)4 * SQ * 1024 * 4;
  float*    cosT  = (float*)ws;                        ws += (size_t)65472 * 4;
  float*    sinT  = (float*)ws;                        ws += (size_t)65472 * 4;
  ushort_t* qbb   = (ushort_t*)ws;                     ws += (size_t)5120 * 2048 * 2;
  ushort_t* kb    = (ushort_t*)ws;                     ws += (size_t)1024 * 512 * 2;
  ushort_t* vtb   = (ushort_t*)ws;                     ws += (size_t)512 * 1024 * 2;
  ushort_t* hbf   = (ushort_t*)ws;                     ws += (size_t)1024 * 2048 * 2;
  ushort_t* akv   = (ushort_t*)ws;                     ws += (size_t)1024 * 4096 * 2;
  ushort_t* oattb = (ushort_t*)ws;                     ws += (size_t)5120 * 2048 * 2;
  ushort_t* wqt   = (ushort_t*)ws;                     ws += (size_t)10240 * 2048 * 2;
  ushort_t* wkvt  = (ushort_t*)ws;                     ws += (size_t)1024 * 4096 * 2;
  ushort_t* wot   = (ushort_t*)ws;                     ws += (size_t)2048 * 2048 * 2;

  k_tables<<<dim3((SQ * 64 + 255) / 256), dim3(256), 0, stream>>>(cosT, sinT);

  // weight transpose+convert
  k_tconv<<<dim3(NQC / 32, HIDC / 32), dim3(256), 0, stream>>>(Wq, wqt, HIDC, NQC);
  k_tconv<<<dim3(NKVC / 32, 4096 / 32), dim3(256), 0, stream>>>(Wkv, wkvt, 4096, NKVC);
  k_tconv<<<dim3(HIDC / 32, HIDC / 32), dim3(256), 0, stream>>>(Wo, wot, HIDC, HIDC);

  // A-matrix converts
  k_f2b<<<dim3((SQ * 2048 / 4 + 255) / 256), dim3(256), 0, stream>>>(hidden + 2048, hbf, SQ * 2048);
  k_concat_b<<<dim3((SQ * 4096 / 4 + 255) / 256), dim3(256), 0, stream>>>(prevh, hidden, akv);

  // q_proj + fused RoPE/scale/bf16 -> qbb   (640 blocks)
  k_gemm_rope<<<dim3(NQC / 128, 8), dim3(256), 0, stream>>>(hbf, wqt, qbb, cosT, sinT);
  // kv = concat(prev,hidden) @ Wkv, split-K x4 (512 blocks)
  k_gemm64<<<dim3(NKVC / 128, 16, 4), dim3(256), 0, stream>>>(akv, wkvt, kvp, SQ, NKVC, 4096, 1024);

  // K rope + V transpose (fold the 4 kv partials)
  k_rope_k<<<dim3((SQ * 4 * 64 + 255) / 256), dim3(256), 0, stream>>>(kvp, kb, cosT, sinT);
  k_vtrans<<<dim3(16, 32), dim3(256), 0, stream>>>(kvp, vtb);

  // MFMA flash attention -> bf16 O
  k_attn_mfma<<<dim3(80, 16), dim3(256), 0, stream>>>(qbb, kb, vtb, oattb);

  // out = O_att @ Wo   (3-buffer counted-vmcnt, 640 blocks)
  k_gemm3buf<<<dim3(HIDC / 128, 40), dim3(256), 0, stream>>>(oattb, wot, out, 5115, HIDC, 2048);
}

// Round 9
// 269.712 us; speedup vs baseline: 1.0623x; 1.0375x over previous
//
#include <hip/hip_runtime.h>
#include <cstddef>
#include <cstdint>

#define SQ    1023
#define HIDC  2048
#define NQC   10240
#define NKVC  1024

typedef unsigned short ushort_t;
typedef __bf16 bf16x8 __attribute__((ext_vector_type(8)));
typedef float  f32x4  __attribute__((ext_vector_type(4)));

__device__ __forceinline__ ushort_t f2bf(float x) {
  union { float f; uint32_t u; } v; v.f = x;
  uint32_t r = v.u + 0x7fffu + ((v.u >> 16) & 1u);   // RNE
  return (ushort_t)(r >> 16);
}

// native f32->bf16 (compiler emits packed cvt; RNE) — hot paths only
__device__ __forceinline__ ushort_t f2bf_fast(float x) {
  __bf16 b = (__bf16)x;
  return __builtin_bit_cast(ushort_t, b);
}

// raw v_exp_f32 (computes 2^x), single value (rare rescale path)
__device__ __forceinline__ float fexp2(float x) {
  float r;
  asm("v_exp_f32 %0, %1\n\ts_nop 0" : "=v"(r) : "v"(x));
  return r;
}

// 4 independent v_exp in one block, in-place; only the last needs the 1
// TRANS wait state before its first consumer -> single s_nop.
__device__ __forceinline__ void fexp2x4(float& a, float& b, float& c, float& d) {
  asm("v_exp_f32 %0, %0\n\t"
      "v_exp_f32 %1, %1\n\t"
      "v_exp_f32 %2, %2\n\t"
      "v_exp_f32 %3, %3\n\t"
      "s_nop 0"
      : "+v"(a), "+v"(b), "+v"(c), "+v"(d));
}

// ======================= RoPE tables =======================
__global__ void k_tables(float* __restrict__ cosT, float* __restrict__ sinT) {
  int idx = blockIdx.x * blockDim.x + threadIdx.x;
  if (idx >= SQ * 64) return;
  int t = idx >> 6, i = idx & 63;
  float inv = powf(10000.0f, -(float)i * (1.0f / 64.0f));
  float f = (float)t * inv;
  cosT[idx] = cosf(f);
  sinT[idx] = sinf(f);
}

// ======================= RoPE + bf16 (K), sums 4 split-K partials =======
__global__ void k_rope_k(const float* __restrict__ kvp, ushort_t* __restrict__ kb,
                         const float* __restrict__ cosT, const float* __restrict__ sinT) {
  int idx = blockIdx.x * blockDim.x + threadIdx.x;
  if (idx >= SQ * 4 * 64) return;
  int d   = idx & 63;
  int kvh = (idx >> 6) & 3;
  int t   = idx >> 8;
  size_t src = (size_t)t * 1024 + kvh * 128 + d;
  float x0 = 0.f, x1 = 0.f;
  #pragma unroll
  for (int z = 0; z < 4; ++z) {
    x0 += kvp[(size_t)z * (SQ * 1024) + src];
    x1 += kvp[(size_t)z * (SQ * 1024) + src + 64];
  }
  float c = cosT[t * 64 + d], s = sinT[t * 64 + d];
  size_t dst = (size_t)t * 512 + kvh * 128 + d;
  kb[dst]      = f2bf(x0 * c - x1 * s);
  kb[dst + 64] = f2bf(x1 * c + x0 * s);
}

// ======================= V transpose (sums 4 partials) =======================
__global__ __launch_bounds__(256)
void k_vtrans(const float* __restrict__ kvp, ushort_t* __restrict__ vt) {
  __shared__ float tile[32][33];
  int v0 = blockIdx.x * 32;
  int t0 = blockIdx.y * 32;
  int r = threadIdx.x >> 5, c = threadIdx.x & 31;
  #pragma unroll
  for (int p = 0; p < 4; ++p) {
    int t = t0 + p * 8 + r;
    float s = 0.f;
    if (t < SQ) {
      size_t src = (size_t)t * 1024 + 512 + v0 + c;
      #pragma unroll
      for (int z = 0; z < 4; ++z) s += kvp[(size_t)z * (SQ * 1024) + src];
    }
    tile[p * 8 + r][c] = s;
  }
  __syncthreads();
  #pragma unroll
  for (int p = 0; p < 4; ++p) {
    int v = v0 + p * 8 + r;
    vt[(size_t)v * 1024 + t0 + c] = f2bf(tile[c][p * 8 + r]);
  }
}

// ============ prep: hbf = bf16(hidden[1:]); akv = bf16([prevh | hidden[:-1]]) =
__global__ void k_prep(const float* __restrict__ hidden, const float* __restrict__ prevh,
                       ushort_t* __restrict__ hbf, ushort_t* __restrict__ akv) {
  int i = (blockIdx.x * blockDim.x + threadIdx.x) * 4;
  if (i >= SQ * 2048) return;
  int r = i >> 11, c = i & 2047;
  float4 h1 = *reinterpret_cast<const float4*>(hidden + (size_t)(r + 1) * 2048 + c);
  float4 h0 = *reinterpret_cast<const float4*>(hidden + (size_t)r * 2048 + c);
  float4 pv = *reinterpret_cast<const float4*>(prevh + (size_t)r * 2048 + c);
  uint2 a, b, d;
  a.x = (uint32_t)f2bf(h1.x) | ((uint32_t)f2bf(h1.y) << 16);
  a.y = (uint32_t)f2bf(h1.z) | ((uint32_t)f2bf(h1.w) << 16);
  b.x = (uint32_t)f2bf(pv.x) | ((uint32_t)f2bf(pv.y) << 16);
  b.y = (uint32_t)f2bf(pv.z) | ((uint32_t)f2bf(pv.w) << 16);
  d.x = (uint32_t)f2bf(h0.x) | ((uint32_t)f2bf(h0.y) << 16);
  d.y = (uint32_t)f2bf(h0.z) | ((uint32_t)f2bf(h0.w) << 16);
  *reinterpret_cast<uint2*>(hbf + i) = a;
  *reinterpret_cast<uint2*>(akv + (size_t)r * 4096 + c) = b;
  *reinterpret_cast<uint2*>(akv + (size_t)r * 4096 + 2048 + c) = d;
}

// ======================= transpose + convert: W [K][N] f32 -> Wt [N][K] bf16 ======
__global__ __launch_bounds__(256)
void k_tconv(const float* __restrict__ in, ushort_t* __restrict__ out, int K, int N) {
  __shared__ float t[32][33];
  int n0 = blockIdx.x * 32, k0 = blockIdx.y * 32;
  int r = threadIdx.x >> 5, c = threadIdx.x & 31;
  #pragma unroll
  for (int p = 0; p < 4; ++p)
    t[p * 8 + r][c] = in[(size_t)(k0 + p * 8 + r) * N + n0 + c];
  __syncthreads();
  #pragma unroll
  for (int p = 0; p < 4; ++p)
    out[(size_t)(n0 + p * 8 + r) * K + k0 + c] = f2bf(t[c][p * 8 + r]);
}

// == GEMM1 + fused RoPE: qbb = rope(hidden[1:] @ Wq) * log2e/sqrt(128), bf16 ===
// 128x128 tile, BK=32, 3-buffer counted-vmcnt. Wave cols REMAPPED so d and d+64
// of the same head live in the same wave/lane: colOff(nj) = wn*32+(nj&1)*16+(nj>>1)*64.
__global__ __launch_bounds__(256)
void k_gemm_rope(const ushort_t* __restrict__ A, const ushort_t* __restrict__ Bt,
                 ushort_t* __restrict__ Q, const float* __restrict__ cosT,
                 const float* __restrict__ sinT)
{
  const int Kd = 2048;
  __shared__ __align__(16) ushort_t As[3][128 * 32];
  __shared__ __align__(16) ushort_t Bs[3][128 * 32];

  const int tid  = threadIdx.x;
  const int lane = tid & 63;
  const int w    = tid >> 6;
  const int wm   = w >> 1, wn = w & 1;
  const int fr   = lane & 15;
  const int kg   = (lane >> 4) * 8;
  const int g4   = lane >> 4;
  const int m0   = blockIdx.y * 128, n0 = blockIdx.x * 128;

  const int lrow = lane >> 2;
  const int lk   = (lane & 3) * 8;

  f32x4 acc[4][4];
  #pragma unroll
  for (int i = 0; i < 4; ++i)
    #pragma unroll
    for (int j = 0; j < 4; ++j) acc[i][j] = (f32x4){0.f, 0.f, 0.f, 0.f};

  auto STAGE = [&](int b, int k0) {
    #pragma unroll
    for (int c = 0; c < 2; ++c) {
      int ch  = w + c * 4;
      int row = ch * 16 + lrow;
      const ushort_t* ga = A  + (size_t)(m0 + row) * Kd + k0 + lk;
      const ushort_t* gb = Bt + (size_t)(n0 + row) * Kd + k0 + lk;
      __builtin_amdgcn_global_load_lds(
          (const __attribute__((address_space(1))) void*)ga,
          (__attribute__((address_space(3))) void*)(&As[b][0] + ch * 512), 16, 0, 0);
      __builtin_amdgcn_global_load_lds(
          (const __attribute__((address_space(1))) void*)gb,
          (__attribute__((address_space(3))) void*)(&Bs[b][0] + ch * 512), 16, 0, 0);
    }
  };

  const int nt = Kd / 32;
  STAGE(0, 0);
  STAGE(1, 32);

  int cur = 0;
  for (int t = 0; t < nt; ++t) {
    if (t + 1 < nt) {
      asm volatile("s_waitcnt vmcnt(4)" ::: "memory");
    } else {
      asm volatile("s_waitcnt vmcnt(0)" ::: "memory");
    }
    __builtin_amdgcn_s_barrier();
    if (t + 2 < nt) {
      int sb = cur + 2; if (sb >= 3) sb -= 3;
      STAGE(sb, (t + 2) * 32);
    }

    bf16x8 av[4], bv[4];
    #pragma unroll
    for (int mi = 0; mi < 4; ++mi)
      av[mi] = *reinterpret_cast<const bf16x8*>(&As[cur][0] + (wm * 64 + mi * 16 + fr) * 32 + kg);
    #pragma unroll
    for (int nj = 0; nj < 4; ++nj) {
      int colOff = wn * 32 + (nj & 1) * 16 + (nj >> 1) * 64;   // remapped
      bv[nj] = *reinterpret_cast<const bf16x8*>(&Bs[cur][0] + (colOff + fr) * 32 + kg);
    }
    #pragma unroll
    for (int mi = 0; mi < 4; ++mi)
      #pragma unroll
      for (int nj = 0; nj < 4; ++nj)
        acc[mi][nj] = __builtin_amdgcn_mfma_f32_16x16x32_bf16(av[mi], bv[nj], acc[mi][nj], 0, 0, 0);

    cur = (cur == 2) ? 0 : cur + 1;
  }

  // fused RoPE epilogue. col = n0 + dd (+64), dd = wn*32 + njp*16 + fr in [0,64)
  const float sc = 0.1275174485f;   // log2(e) / sqrt(128)
  const int nChunk = n0 >> 11;
  #pragma unroll
  for (int mi = 0; mi < 4; ++mi) {
    #pragma unroll
    for (int r = 0; r < 4; ++r) {
      int gr = m0 + wm * 64 + mi * 16 + g4 * 4 + r;
      if (gr >= SQ) continue;
      int st  = gr * 5 + nChunk;
      int tau = st % 1023;
      const float* ct = cosT + tau * 64;
      const float* stb = sinT + tau * 64;
      #pragma unroll
      for (int njp = 0; njp < 2; ++njp) {
        int dd = wn * 32 + njp * 16 + fr;
        float c = ct[dd], s = stb[dd];
        float x0 = acc[mi][njp][r];
        float x1 = acc[mi][njp + 2][r];
        size_t base = (size_t)gr * 10240 + n0 + dd;
        Q[base]      = f2bf_fast((x0 * c - x1 * s) * sc);
        Q[base + 64] = f2bf_fast((x1 * c + x0 * s) * sc);
      }
    }
  }
}

// == bf16 MFMA GEMM, 128x128 tile, BK=32, 3-buffer + counted vmcnt (GEMM3) ====
__global__ __launch_bounds__(256)
void k_gemm3buf(const ushort_t* __restrict__ A, const ushort_t* __restrict__ Bt,
                float* __restrict__ C, int M, int N, int Kd)
{
  __shared__ __align__(16) ushort_t As[3][128 * 32];
  __shared__ __align__(16) ushort_t Bs[3][128 * 32];

  const int tid  = threadIdx.x;
  const int lane = tid & 63;
  const int w    = tid >> 6;
  const int wm   = w >> 1, wn = w & 1;
  const int fr   = lane & 15;
  const int kg   = (lane >> 4) * 8;
  const int m0   = blockIdx.y * 128, n0 = blockIdx.x * 128;

  const int lrow = lane >> 2;
  const int lk   = (lane & 3) * 8;

  f32x4 acc[4][4];
  #pragma unroll
  for (int i = 0; i < 4; ++i)
    #pragma unroll
    for (int j = 0; j < 4; ++j) acc[i][j] = (f32x4){0.f, 0.f, 0.f, 0.f};

  auto STAGE = [&](int b, int k0) {
    #pragma unroll
    for (int c = 0; c < 2; ++c) {
      int ch  = w + c * 4;
      int row = ch * 16 + lrow;
      const ushort_t* ga = A  + (size_t)(m0 + row) * Kd + k0 + lk;
      const ushort_t* gb = Bt + (size_t)(n0 + row) * Kd + k0 + lk;
      __builtin_amdgcn_global_load_lds(
          (const __attribute__((address_space(1))) void*)ga,
          (__attribute__((address_space(3))) void*)(&As[b][0] + ch * 512), 16, 0, 0);
      __builtin_amdgcn_global_load_lds(
          (const __attribute__((address_space(1))) void*)gb,
          (__attribute__((address_space(3))) void*)(&Bs[b][0] + ch * 512), 16, 0, 0);
    }
  };

  const int nt = Kd / 32;
  STAGE(0, 0);
  STAGE(1, 32);

  int cur = 0;
  for (int t = 0; t < nt; ++t) {
    if (t + 1 < nt) {
      asm volatile("s_waitcnt vmcnt(4)" ::: "memory");
    } else {
      asm volatile("s_waitcnt vmcnt(0)" ::: "memory");
    }
    __builtin_amdgcn_s_barrier();
    if (t + 2 < nt) {
      int sb = cur + 2; if (sb >= 3) sb -= 3;
      STAGE(sb, (t + 2) * 32);
    }

    bf16x8 av[4], bv[4];
    #pragma unroll
    for (int mi = 0; mi < 4; ++mi)
      av[mi] = *reinterpret_cast<const bf16x8*>(&As[cur][0] + (wm * 64 + mi * 16 + fr) * 32 + kg);
    #pragma unroll
    for (int nj = 0; nj < 4; ++nj)
      bv[nj] = *reinterpret_cast<const bf16x8*>(&Bs[cur][0] + (wn * 64 + nj * 16 + fr) * 32 + kg);
    #pragma unroll
    for (int mi = 0; mi < 4; ++mi)
      #pragma unroll
      for (int nj = 0; nj < 4; ++nj)
        acc[mi][nj] = __builtin_amdgcn_mfma_f32_16x16x32_bf16(av[mi], bv[nj], acc[mi][nj], 0, 0, 0);

    cur = (cur == 2) ? 0 : cur + 1;
  }

  #pragma unroll
  for (int mi = 0; mi < 4; ++mi) {
    #pragma unroll
    for (int nj = 0; nj < 4; ++nj) {
      int rbase = m0 + wm * 64 + mi * 16 + (lane >> 4) * 4;
      int col   = n0 + wn * 64 + nj * 16 + fr;
      #pragma unroll
      for (int r = 0; r < 4; ++r) {
        int gr = rbase + r;
        if (gr < M) C[(size_t)gr * N + col] = acc[mi][nj][r];
      }
    }
  }
}

// ======================= bf16 MFMA GEMM, 64x128 tile (GEMM2 split-K) =========
__global__ __launch_bounds__(256)
void k_gemm64(const ushort_t* __restrict__ A, const ushort_t* __restrict__ Bt,
              float* __restrict__ C, int M, int N, int Kd, int kLen)
{
  __shared__ __align__(16) ushort_t As[64 * 32];
  __shared__ __align__(16) ushort_t Bs[128 * 32];

  const int tid  = threadIdx.x;
  const int lane = tid & 63;
  const int w    = tid >> 6;
  const int wm   = w >> 1, wn = w & 1;
  const int fr   = lane & 15;
  const int kg   = (lane >> 4) * 8;
  const int g4   = lane >> 4;
  const int l15  = lane & 15;
  const int m0   = blockIdx.y * 64, n0 = blockIdx.x * 128;
  const int kOff = blockIdx.z * kLen;
  C += (size_t)blockIdx.z * M * N;

  const int arow = tid >> 2, aslot = (tid & 3) * 8;

  f32x4 acc[2][4];
  #pragma unroll
  for (int i = 0; i < 2; ++i)
    #pragma unroll
    for (int j = 0; j < 4; ++j) acc[i][j] = (f32x4){0.f, 0.f, 0.f, 0.f};

  for (int k0 = kOff; k0 < kOff + kLen; k0 += 32) {
    {
      const ushort_t* ga = A + (size_t)(m0 + arow) * Kd + k0 + aslot;
      __builtin_amdgcn_global_load_lds(
          (const __attribute__((address_space(1))) void*)ga,
          (__attribute__((address_space(3))) void*)(As + w * 512), 16, 0, 0);
    }
    #pragma unroll
    for (int c = 0; c < 2; ++c) {
      int u = c * 256 + tid;
      const ushort_t* gb = Bt + (size_t)(n0 + (u >> 2)) * Kd + k0 + (u & 3) * 8;
      __builtin_amdgcn_global_load_lds(
          (const __attribute__((address_space(1))) void*)gb,
          (__attribute__((address_space(3))) void*)(Bs + (c * 256 + w * 64) * 8), 16, 0, 0);
    }
    __syncthreads();

    bf16x8 av[2], bv[4];
    #pragma unroll
    for (int mi = 0; mi < 2; ++mi)
      av[mi] = *reinterpret_cast<const bf16x8*>(As + (wm * 32 + mi * 16 + fr) * 32 + kg);
    #pragma unroll
    for (int nj = 0; nj < 4; ++nj)
      bv[nj] = *reinterpret_cast<const bf16x8*>(Bs + (wn * 64 + nj * 16 + fr) * 32 + kg);
    #pragma unroll
    for (int mi = 0; mi < 2; ++mi)
      #pragma unroll
      for (int nj = 0; nj < 4; ++nj)
        acc[mi][nj] = __builtin_amdgcn_mfma_f32_16x16x32_bf16(av[mi], bv[nj], acc[mi][nj], 0, 0, 0);
    __syncthreads();
  }

  #pragma unroll
  for (int mi = 0; mi < 2; ++mi) {
    #pragma unroll
    for (int nj = 0; nj < 4; ++nj) {
      int rbase = m0 + wm * 32 + mi * 16 + g4 * 4;
      int col   = n0 + wn * 64 + nj * 16 + l15;
      #pragma unroll
      for (int r = 0; r < 4; ++r) {
        int gr = rbase + r;
        if (gr < M) C[(size_t)gr * N + col] = acc[mi][nj][r];
      }
    }
  }
}

// ======================= MFMA flash attention (exp2 domain) ==================
// grid (80, 16): x = g*16+h, y -> qt = 15 - y (heavy first). 256 thr = 4 waves.
// Q pre-scaled by log2(e)/sqrt(128). Softmax denominator l computed via an
// extra PV-MFMA with all-ones B-frag (rowsum lands in every lane's acc_l).
__global__ __launch_bounds__(256)
void k_attn_mfma(const ushort_t* __restrict__ qb, const ushort_t* __restrict__ kb,
                 const ushort_t* __restrict__ vt, ushort_t* __restrict__ oattb)
{
  __shared__ __align__(16) ushort_t Ks[64 * 128];   // [kv][128 d], slot s holds d-slot s^(kv&7)
  __shared__ __align__(16) ushort_t Vs[128 * 64];   // [d][64 kv], slot s holds kv-slot s^(d&7)
  __shared__ __align__(16) ushort_t Ps[4][16 * 64]; // per-wave P [16 q][64 kv], swizzled

  const int tid  = threadIdx.x;
  const int lane = tid & 63;
  const int w    = tid >> 6;
  const int l15  = lane & 15;
  const int g4   = lane >> 4;
  const int gh   = blockIdx.x;
  const int g = gh >> 4, h = gh & 15, kvh = (gh & 15) >> 2;
  const int qt = 15 - blockIdx.y;
  const int t0 = qt * 64;

  bf16x8 av[4];
  {
    int t = t0 + w * 16 + l15;
    const ushort_t* qrow = qb + (((size_t)(g * SQ + t)) * 16 + h) * 128;
    #pragma unroll
    for (int kk = 0; kk < 4; ++kk)
      av[kk] = *reinterpret_cast<const bf16x8*>(qrow + kk * 32 + g4 * 8);
  }

  bf16x8 ones;
  #pragma unroll
  for (int j = 0; j < 8; ++j) ones[j] = __builtin_bit_cast(__bf16, (ushort_t)0x3F80);

  f32x4 acc[8];
  #pragma unroll
  for (int dt = 0; dt < 8; ++dt) acc[dt] = (f32x4){0.f, 0.f, 0.f, 0.f};
  f32x4 acc_l = (f32x4){0.f, 0.f, 0.f, 0.f};
  float m[4];
  #pragma unroll
  for (int r = 0; r < 4; ++r) m[r] = -1e30f;

  ushort_t* pw = &Ps[w][0];

  for (int jt = 0; jt <= qt; ++jt) {
    int u0 = jt * 64;
    #pragma unroll
    for (int i = 0; i < 4; ++i) {
      int c = (w * 4 + i) * 64 + lane;
      int kv = c >> 4, sl = c & 15;
      const ushort_t* srck = kb + (size_t)(u0 + kv) * 512 + kvh * 128 + ((sl ^ (kv & 7)) << 3);
      __builtin_amdgcn_global_load_lds(
          (const __attribute__((address_space(1))) void*)srck,
          (__attribute__((address_space(3))) void*)(Ks + (w * 4 + i) * 512), 16, 0, 0);
      int d = c >> 3, sv = c & 7;
      const ushort_t* srcv = vt + (size_t)(kvh * 128 + d) * 1024 + u0 + ((sv ^ (d & 7)) << 3);
      __builtin_amdgcn_global_load_lds(
          (const __attribute__((address_space(1))) void*)srcv,
          (__attribute__((address_space(3))) void*)(Vs + (w * 4 + i) * 512), 16, 0, 0);
    }
    __syncthreads();

    f32x4 S[4];
    #pragma unroll
    for (int ct = 0; ct < 4; ++ct) S[ct] = (f32x4){0.f, 0.f, 0.f, 0.f};
    #pragma unroll
    for (int ct = 0; ct < 4; ++ct) {
      int kv = ct * 16 + l15;
      #pragma unroll
      for (int kk = 0; kk < 4; ++kk) {
        bf16x8 bv = *reinterpret_cast<const bf16x8*>(
            Ks + kv * 128 + ((((kk << 2) | g4) ^ (kv & 7)) << 3));
        S[ct] = __builtin_amdgcn_mfma_f32_16x16x32_bf16(av[kk], bv, S[ct], 0, 0, 0);
      }
    }
    if (jt == qt) {
      #pragma unroll
      for (int ct = 0; ct < 4; ++ct) {
        int u = u0 + ct * 16 + l15;
        #pragma unroll
        for (int r = 0; r < 4; ++r) {
          int t = t0 + w * 16 + g4 * 4 + r;
          if (u > t) S[ct][r] = -1e30f;
        }
      }
    }
    // tile max per row
    float tm[4];
    #pragma unroll
    for (int r = 0; r < 4; ++r) {
      float t1 = fmaxf(fmaxf(S[0][r], S[1][r]), fmaxf(S[2][r], S[3][r]));
      t1 = fmaxf(t1, __shfl_xor(t1, 1));
      t1 = fmaxf(t1, __shfl_xor(t1, 2));
      t1 = fmaxf(t1, __shfl_xor(t1, 4));
      t1 = fmaxf(t1, __shfl_xor(t1, 8));
      tm[r] = t1;
    }
    // defer-max (T13): only rescale when some row grew past m + 8 (log2 units)
    bool need = (tm[0] > m[0] + 8.f) || (tm[1] > m[1] + 8.f) ||
                (tm[2] > m[2] + 8.f) || (tm[3] > m[3] + 8.f);
    if (__any(need)) {
      #pragma unroll
      for (int r = 0; r < 4; ++r) {
        float mn = fmaxf(m[r], tm[r]);
        float corr = fexp2(m[r] - mn);
        m[r] = mn;
        acc_l[r] *= corr;
        #pragma unroll
        for (int dt = 0; dt < 8; ++dt) acc[dt][r] *= corr;
      }
    }
    // P = 2^(S - m), batched v_exp
    #pragma unroll
    for (int r = 0; r < 4; ++r) {
      float e0 = S[0][r] - m[r];
      float e1 = S[1][r] - m[r];
      float e2 = S[2][r] - m[r];
      float e3 = S[3][r] - m[r];
      fexp2x4(e0, e1, e2, e3);
      S[0][r] = e0; S[1][r] = e1; S[2][r] = e2; S[3][r] = e3;
    }

    #pragma unroll
    for (int ct = 0; ct < 4; ++ct) {
      int kv = ct * 16 + l15;
      #pragma unroll
      for (int r = 0; r < 4; ++r) {
        int q = g4 * 4 + r;
        pw[q * 64 + ((((kv >> 3) ^ (q & 7)) << 3) | (kv & 7))] = f2bf_fast(S[ct][r]);
      }
    }
    #pragma unroll
    for (int kk = 0; kk < 2; ++kk) {
      bf16x8 pa = *reinterpret_cast<const bf16x8*>(
          pw + l15 * 64 + ((((kk << 2) | g4) ^ (l15 & 7)) << 3));
      acc_l = __builtin_amdgcn_mfma_f32_16x16x32_bf16(pa, ones, acc_l, 0, 0, 0);
      #pragma unroll
      for (int dt = 0; dt < 8; ++dt) {
        int d = dt * 16 + l15;
        bf16x8 vv = *reinterpret_cast<const bf16x8*>(
            Vs + d * 64 + ((((kk << 2) | g4) ^ (d & 7)) << 3));
        acc[dt] = __builtin_amdgcn_mfma_f32_16x16x32_bf16(pa, vv, acc[dt], 0, 0, 0);
      }
    }
    __syncthreads();
  }

  #pragma unroll
  for (int r = 0; r < 4; ++r) {
    int t = t0 + w * 16 + g4 * 4 + r;
    if (t >= SQ) continue;
    float inv = 1.f / acc_l[r];
    ushort_t* dst = oattb + ((size_t)(g * SQ + t)) * 2048 + h * 128;
    #pragma unroll
    for (int dt = 0; dt < 8; ++dt)
      dst[dt * 16 + l15] = f2bf_fast(acc[dt][r] * inv);
  }
}

// ======================= launch =======================
extern "C" void kernel_launch(void* const* d_in, const int* in_sizes, int n_in,
                              void* d_out, int out_size, void* d_ws, size_t ws_size,
                              hipStream_t stream) {
  const float* hidden = (const float*)d_in[0];   // (1024, 2048)
  const float* prevh  = (const float*)d_in[1];   // (1023, 2048)
  const float* Wq     = (const float*)d_in[4];   // (2048, 10240)
  const float* Wkv    = (const float*)d_in[5];   // (4096, 1024)
  const float* Wo     = (const float*)d_in[6];   // (2048, 2048)
  float* out = (float*)d_out;                    // (5115, 2048)

  char* ws = (char*)d_ws;
  float*    kvp   = (float*)ws;                        ws += (size_t)4 * SQ * 1024 * 4;
  float*    cosT  = (float*)ws;                        ws += (size_t)65472 * 4;
  float*    sinT  = (float*)ws;                        ws += (size_t)65472 * 4;
  ushort_t* qbb   = (ushort_t*)ws;                     ws += (size_t)5120 * 2048 * 2;
  ushort_t* kb    = (ushort_t*)ws;                     ws += (size_t)1024 * 512 * 2;
  ushort_t* vtb   = (ushort_t*)ws;                     ws += (size_t)512 * 1024 * 2;
  ushort_t* hbf   = (ushort_t*)ws;                     ws += (size_t)1024 * 2048 * 2;
  ushort_t* akv   = (ushort_t*)ws;                     ws += (size_t)1024 * 4096 * 2;
  ushort_t* oattb = (ushort_t*)ws;                     ws += (size_t)5120 * 2048 * 2;
  ushort_t* wqt   = (ushort_t*)ws;                     ws += (size_t)10240 * 2048 * 2;
  ushort_t* wkvt  = (ushort_t*)ws;                     ws += (size_t)1024 * 4096 * 2;
  ushort_t* wot   = (ushort_t*)ws;                     ws += (size_t)2048 * 2048 * 2;

  k_tables<<<dim3((SQ * 64 + 255) / 256), dim3(256), 0, stream>>>(cosT, sinT);

  // weight transpose+convert
  k_tconv<<<dim3(NQC / 32, HIDC / 32), dim3(256), 0, stream>>>(Wq, wqt, HIDC, NQC);
  k_tconv<<<dim3(NKVC / 32, 4096 / 32), dim3(256), 0, stream>>>(Wkv, wkvt, 4096, NKVC);
  k_tconv<<<dim3(HIDC / 32, HIDC / 32), dim3(256), 0, stream>>>(Wo, wot, HIDC, HIDC);

  // A-matrix converts (fused)
  k_prep<<<dim3((SQ * 2048 / 4 + 255) / 256), dim3(256), 0, stream>>>(hidden, prevh, hbf, akv);

  // q_proj + fused RoPE/scale/bf16 -> qbb   (640 blocks)
  k_gemm_rope<<<dim3(NQC / 128, 8), dim3(256), 0, stream>>>(hbf, wqt, qbb, cosT, sinT);
  // kv = concat(prev,hidden) @ Wkv, split-K x4 (512 blocks)
  k_gemm64<<<dim3(NKVC / 128, 16, 4), dim3(256), 0, stream>>>(akv, wkvt, kvp, SQ, NKVC, 4096, 1024);

  // K rope + V transpose (fold the 4 kv partials)
  k_rope_k<<<dim3((SQ * 4 * 64 + 255) / 256), dim3(256), 0, stream>>>(kvp, kb, cosT, sinT);
  k_vtrans<<<dim3(16, 32), dim3(256), 0, stream>>>(kvp, vtb);

  // MFMA flash attention -> bf16 O
  k_attn_mfma<<<dim3(80, 16), dim3(256), 0, stream>>>(qbb, kb, vtb, oattb);

  // out = O_att @ Wo   (3-buffer counted-vmcnt, 640 blocks)
  k_gemm3buf<<<dim3(HIDC / 128, 40), dim3(256), 0, stream>>>(oattb, wot, out, 5115, HIDC, 2048);
}

// Round 10
// 245.605 us; speedup vs baseline: 1.1665x; 1.0982x over previous
//
#include <hip/hip_runtime.h>
#include <cstddef>
#include <cstdint>

#define SQ    1023
#define HIDC  2048
#define NQC   10240
#define NKVC  1024

typedef unsigned short ushort_t;
typedef __bf16 bf16x8 __attribute__((ext_vector_type(8)));
typedef float  f32x4  __attribute__((ext_vector_type(4)));

__device__ __forceinline__ ushort_t f2bf(float x) {
  union { float f; uint32_t u; } v; v.f = x;
  uint32_t r = v.u + 0x7fffu + ((v.u >> 16) & 1u);   // RNE
  return (ushort_t)(r >> 16);
}

__device__ __forceinline__ ushort_t f2bf_fast(float x) {
  __bf16 b = (__bf16)x;
  return __builtin_bit_cast(ushort_t, b);
}

// raw v_exp_f32 (computes 2^x)
__device__ __forceinline__ float fexp2(float x) {
  float r;
  asm("v_exp_f32 %0, %1\n\ts_nop 0" : "=v"(r) : "v"(x));
  return r;
}

__device__ __forceinline__ void fexp2x4(float& a, float& b, float& c, float& d) {
  asm("v_exp_f32 %0, %0\n\t"
      "v_exp_f32 %1, %1\n\t"
      "v_exp_f32 %2, %2\n\t"
      "v_exp_f32 %3, %3\n\t"
      "s_nop 0"
      : "+v"(a), "+v"(b), "+v"(c), "+v"(d));
}

// ================= k_pre: tables U tconv(Wq,Wkv,Wo) U prep (one dispatch) ====
// block roles: [0,20480) tconv Wq | [20480,24576) tconv Wkv | [24576,28672)
// tconv Wo | [28672,30718) prep | [30718,30974) rope tables.
__device__ __forceinline__ void tconv_body(const float* __restrict__ in,
                                           ushort_t* __restrict__ out,
                                           int K, int N, int bx, int by,
                                           int tid, float (&t)[32][33]) {
  int n0 = bx * 32, k0 = by * 32;
  int r = tid >> 5, c = tid & 31;
  #pragma unroll
  for (int p = 0; p < 4; ++p)
    t[p * 8 + r][c] = in[(size_t)(k0 + p * 8 + r) * N + n0 + c];
  __syncthreads();
  #pragma unroll
  for (int p = 0; p < 4; ++p)
    out[(size_t)(n0 + p * 8 + r) * K + k0 + c] = f2bf(t[c][p * 8 + r]);
}

__global__ __launch_bounds__(256)
void k_pre(const float* __restrict__ Wq, const float* __restrict__ Wkv,
           const float* __restrict__ Wo, const float* __restrict__ hidden,
           const float* __restrict__ prevh,
           ushort_t* __restrict__ wqt, ushort_t* __restrict__ wkvt,
           ushort_t* __restrict__ wot, ushort_t* __restrict__ hbf,
           ushort_t* __restrict__ akv,
           float* __restrict__ cosT, float* __restrict__ sinT)
{
  __shared__ float tsh[32][33];
  const int tid = threadIdx.x;
  int b = blockIdx.x;
  if (b < 20480) { tconv_body(Wq, wqt, HIDC, NQC, b % 320, b / 320, tid, tsh); return; }
  b -= 20480;
  if (b < 4096)  { tconv_body(Wkv, wkvt, 4096, NKVC, b % 32, b / 32, tid, tsh); return; }
  b -= 4096;
  if (b < 4096)  { tconv_body(Wo, wot, HIDC, HIDC, b % 64, b / 64, tid, tsh); return; }
  b -= 4096;
  if (b < 2046) {
    int i = (b * 256 + tid) * 4;
    if (i >= SQ * 2048) return;
    int r = i >> 11, c = i & 2047;
    float4 h1 = *reinterpret_cast<const float4*>(hidden + (size_t)(r + 1) * 2048 + c);
    float4 h0 = *reinterpret_cast<const float4*>(hidden + (size_t)r * 2048 + c);
    float4 pv = *reinterpret_cast<const float4*>(prevh + (size_t)r * 2048 + c);
    uint2 a, bb, d;
    a.x  = (uint32_t)f2bf(h1.x) | ((uint32_t)f2bf(h1.y) << 16);
    a.y  = (uint32_t)f2bf(h1.z) | ((uint32_t)f2bf(h1.w) << 16);
    bb.x = (uint32_t)f2bf(pv.x) | ((uint32_t)f2bf(pv.y) << 16);
    bb.y = (uint32_t)f2bf(pv.z) | ((uint32_t)f2bf(pv.w) << 16);
    d.x  = (uint32_t)f2bf(h0.x) | ((uint32_t)f2bf(h0.y) << 16);
    d.y  = (uint32_t)f2bf(h0.z) | ((uint32_t)f2bf(h0.w) << 16);
    *reinterpret_cast<uint2*>(hbf + i) = a;
    *reinterpret_cast<uint2*>(akv + (size_t)r * 4096 + c) = bb;
    *reinterpret_cast<uint2*>(akv + (size_t)r * 4096 + 2048 + c) = d;
    return;
  }
  b -= 2046;
  {
    int idx = b * 256 + tid;
    if (idx >= SQ * 64) return;
    int t = idx >> 6, i = idx & 63;
    float inv = powf(10000.0f, -(float)i * (1.0f / 64.0f));
    float f = (float)t * inv;
    cosT[idx] = cosf(f);
    sinT[idx] = sinf(f);
  }
}

// ======== k_gemms: GEMM1+RoPE (blocks 0-639) U GEMM2 split-K (640-1151) ======
__global__ __launch_bounds__(256)
void k_gemms(const ushort_t* __restrict__ hbf, const ushort_t* __restrict__ wqt,
             ushort_t* __restrict__ qbb, const float* __restrict__ cosT,
             const float* __restrict__ sinT,
             const ushort_t* __restrict__ akv, const ushort_t* __restrict__ wkvt,
             float* __restrict__ kvp)
{
  __shared__ __align__(16) ushort_t As[3][128 * 32];
  __shared__ __align__(16) ushort_t Bs[3][128 * 32];

  const int tid  = threadIdx.x;
  const int lane = tid & 63;
  const int w    = tid >> 6;
  const int wm   = w >> 1, wn = w & 1;
  const int fr   = lane & 15;
  const int kg   = (lane >> 4) * 8;
  const int g4   = lane >> 4;
  const int lrow = lane >> 2;
  const int lk   = (lane & 3) * 8;

  if (blockIdx.x < 640) {
    // ---------------- GEMM1 + fused RoPE (m97 3-buffer counted-vmcnt) -------
    const int Kd = 2048;
    const int m0 = (blockIdx.x / 80) * 128, n0 = (blockIdx.x % 80) * 128;
    const ushort_t* A  = hbf;
    const ushort_t* Bt = wqt;

    f32x4 acc[4][4];
    #pragma unroll
    for (int i = 0; i < 4; ++i)
      #pragma unroll
      for (int j = 0; j < 4; ++j) acc[i][j] = (f32x4){0.f, 0.f, 0.f, 0.f};

    auto STAGE = [&](int b, int k0) {
      #pragma unroll
      for (int c = 0; c < 2; ++c) {
        int ch  = w + c * 4;
        int row = ch * 16 + lrow;
        const ushort_t* ga = A  + (size_t)(m0 + row) * Kd + k0 + lk;
        const ushort_t* gb = Bt + (size_t)(n0 + row) * Kd + k0 + lk;
        __builtin_amdgcn_global_load_lds(
            (const __attribute__((address_space(1))) void*)ga,
            (__attribute__((address_space(3))) void*)(&As[b][0] + ch * 512), 16, 0, 0);
        __builtin_amdgcn_global_load_lds(
            (const __attribute__((address_space(1))) void*)gb,
            (__attribute__((address_space(3))) void*)(&Bs[b][0] + ch * 512), 16, 0, 0);
      }
    };

    const int nt = Kd / 32;
    STAGE(0, 0);
    STAGE(1, 32);

    int cur = 0;
    for (int t = 0; t < nt; ++t) {
      if (t + 1 < nt) {
        asm volatile("s_waitcnt vmcnt(4)" ::: "memory");
      } else {
        asm volatile("s_waitcnt vmcnt(0)" ::: "memory");
      }
      __builtin_amdgcn_s_barrier();
      if (t + 2 < nt) {
        int sb = cur + 2; if (sb >= 3) sb -= 3;
        STAGE(sb, (t + 2) * 32);
      }

      bf16x8 av[4], bv[4];
      #pragma unroll
      for (int mi = 0; mi < 4; ++mi)
        av[mi] = *reinterpret_cast<const bf16x8*>(&As[cur][0] + (wm * 64 + mi * 16 + fr) * 32 + kg);
      #pragma unroll
      for (int nj = 0; nj < 4; ++nj) {
        int colOff = wn * 32 + (nj & 1) * 16 + (nj >> 1) * 64;   // remapped for RoPE pairing
        bv[nj] = *reinterpret_cast<const bf16x8*>(&Bs[cur][0] + (colOff + fr) * 32 + kg);
      }
      #pragma unroll
      for (int mi = 0; mi < 4; ++mi)
        #pragma unroll
        for (int nj = 0; nj < 4; ++nj)
          acc[mi][nj] = __builtin_amdgcn_mfma_f32_16x16x32_bf16(av[mi], bv[nj], acc[mi][nj], 0, 0, 0);

      cur = (cur == 2) ? 0 : cur + 1;
    }

    const float sc = 0.1275174485f;   // log2(e) / sqrt(128)
    const int nChunk = n0 >> 11;
    #pragma unroll
    for (int mi = 0; mi < 4; ++mi) {
      #pragma unroll
      for (int r = 0; r < 4; ++r) {
        int gr = m0 + wm * 64 + mi * 16 + g4 * 4 + r;
        if (gr >= SQ) continue;
        int st  = gr * 5 + nChunk;
        int tau = st % 1023;
        const float* ct  = cosT + tau * 64;
        const float* stb = sinT + tau * 64;
        #pragma unroll
        for (int njp = 0; njp < 2; ++njp) {
          int dd = wn * 32 + njp * 16 + fr;
          float c = ct[dd], s = stb[dd];
          float x0 = acc[mi][njp][r];
          float x1 = acc[mi][njp + 2][r];
          size_t base = (size_t)gr * 10240 + n0 + dd;
          qbb[base]      = f2bf_fast((x0 * c - x1 * s) * sc);
          qbb[base + 64] = f2bf_fast((x1 * c + x0 * s) * sc);
        }
      }
    }
  } else {
    // ---------------- GEMM2 64x128 split-K x4 (uses As[0]/Bs[0] regions) ----
    const int u = blockIdx.x - 640;
    const int Kd = 4096, M = SQ, N = NKVC, kLen = 1024;
    const int n0 = (u & 7) * 128, m0 = ((u >> 3) & 15) * 64;
    const int kOff = (u >> 7) * kLen;
    float* C = kvp + (size_t)(u >> 7) * M * N;
    ushort_t* As64 = &As[0][0];
    ushort_t* Bs64 = &Bs[0][0];

    const int arow = tid >> 2, aslot = (tid & 3) * 8;
    const int l15 = lane & 15;

    f32x4 acc[2][4];
    #pragma unroll
    for (int i = 0; i < 2; ++i)
      #pragma unroll
      for (int j = 0; j < 4; ++j) acc[i][j] = (f32x4){0.f, 0.f, 0.f, 0.f};

    for (int k0 = kOff; k0 < kOff + kLen; k0 += 32) {
      {
        const ushort_t* ga = akv + (size_t)(m0 + arow) * Kd + k0 + aslot;
        __builtin_amdgcn_global_load_lds(
            (const __attribute__((address_space(1))) void*)ga,
            (__attribute__((address_space(3))) void*)(As64 + w * 512), 16, 0, 0);
      }
      #pragma unroll
      for (int c = 0; c < 2; ++c) {
        int uu = c * 256 + tid;
        const ushort_t* gb = wkvt + (size_t)(n0 + (uu >> 2)) * Kd + k0 + (uu & 3) * 8;
        __builtin_amdgcn_global_load_lds(
            (const __attribute__((address_space(1))) void*)gb,
            (__attribute__((address_space(3))) void*)(Bs64 + (c * 256 + w * 64) * 8), 16, 0, 0);
      }
      __syncthreads();

      bf16x8 av[2], bv[4];
      #pragma unroll
      for (int mi = 0; mi < 2; ++mi)
        av[mi] = *reinterpret_cast<const bf16x8*>(As64 + (wm * 32 + mi * 16 + fr) * 32 + kg);
      #pragma unroll
      for (int nj = 0; nj < 4; ++nj)
        bv[nj] = *reinterpret_cast<const bf16x8*>(Bs64 + (wn * 64 + nj * 16 + fr) * 32 + kg);
      #pragma unroll
      for (int mi = 0; mi < 2; ++mi)
        #pragma unroll
        for (int nj = 0; nj < 4; ++nj)
          acc[mi][nj] = __builtin_amdgcn_mfma_f32_16x16x32_bf16(av[mi], bv[nj], acc[mi][nj], 0, 0, 0);
      __syncthreads();
    }

    #pragma unroll
    for (int mi = 0; mi < 2; ++mi) {
      #pragma unroll
      for (int nj = 0; nj < 4; ++nj) {
        int rbase = m0 + wm * 32 + mi * 16 + g4 * 4;
        int col   = n0 + wn * 64 + nj * 16 + l15;
        #pragma unroll
        for (int r = 0; r < 4; ++r) {
          int gr = rbase + r;
          if (gr < M) C[(size_t)gr * N + col] = acc[mi][nj][r];
        }
      }
    }
  }
}

// ============ k_kv: rope_k (blocks 0-1022) U vtrans (blocks 1023-1534) =======
__global__ __launch_bounds__(256)
void k_kv(const float* __restrict__ kvp, ushort_t* __restrict__ kb,
          ushort_t* __restrict__ vt, const float* __restrict__ cosT,
          const float* __restrict__ sinT)
{
  __shared__ float tile[32][33];
  const int tid = threadIdx.x;
  int b = blockIdx.x;
  if (b < 1023) {
    int idx = b * 256 + tid;
    if (idx >= SQ * 4 * 64) return;
    int d   = idx & 63;
    int kvh = (idx >> 6) & 3;
    int t   = idx >> 8;
    size_t src = (size_t)t * 1024 + kvh * 128 + d;
    float x0 = 0.f, x1 = 0.f;
    #pragma unroll
    for (int z = 0; z < 4; ++z) {
      x0 += kvp[(size_t)z * (SQ * 1024) + src];
      x1 += kvp[(size_t)z * (SQ * 1024) + src + 64];
    }
    float c = cosT[t * 64 + d], s = sinT[t * 64 + d];
    size_t dst = (size_t)t * 512 + kvh * 128 + d;
    kb[dst]      = f2bf(x0 * c - x1 * s);
    kb[dst + 64] = f2bf(x1 * c + x0 * s);
    return;
  }
  b -= 1023;
  {
    int v0 = (b & 15) * 32;
    int t0 = (b >> 4) * 32;
    int r = tid >> 5, c = tid & 31;
    #pragma unroll
    for (int p = 0; p < 4; ++p) {
      int t = t0 + p * 8 + r;
      float s = 0.f;
      if (t < SQ) {
        size_t src = (size_t)t * 1024 + 512 + v0 + c;
        #pragma unroll
        for (int z = 0; z < 4; ++z) s += kvp[(size_t)z * (SQ * 1024) + src];
      }
      tile[p * 8 + r][c] = s;
    }
    __syncthreads();
    #pragma unroll
    for (int p = 0; p < 4; ++p) {
      int v = v0 + p * 8 + r;
      vt[(size_t)v * 1024 + t0 + c] = f2bf(tile[c][p * 8 + r]);
    }
  }
}

// == bf16 MFMA GEMM, 128x128 tile, BK=32, 3-buffer + counted vmcnt (GEMM3) ====
__global__ __launch_bounds__(256)
void k_gemm3buf(const ushort_t* __restrict__ A, const ushort_t* __restrict__ Bt,
                float* __restrict__ C, int M, int N, int Kd)
{
  __shared__ __align__(16) ushort_t As[3][128 * 32];
  __shared__ __align__(16) ushort_t Bs[3][128 * 32];

  const int tid  = threadIdx.x;
  const int lane = tid & 63;
  const int w    = tid >> 6;
  const int wm   = w >> 1, wn = w & 1;
  const int fr   = lane & 15;
  const int kg   = (lane >> 4) * 8;
  const int m0   = blockIdx.y * 128, n0 = blockIdx.x * 128;

  const int lrow = lane >> 2;
  const int lk   = (lane & 3) * 8;

  f32x4 acc[4][4];
  #pragma unroll
  for (int i = 0; i < 4; ++i)
    #pragma unroll
    for (int j = 0; j < 4; ++j) acc[i][j] = (f32x4){0.f, 0.f, 0.f, 0.f};

  auto STAGE = [&](int b, int k0) {
    #pragma unroll
    for (int c = 0; c < 2; ++c) {
      int ch  = w + c * 4;
      int row = ch * 16 + lrow;
      const ushort_t* ga = A  + (size_t)(m0 + row) * Kd + k0 + lk;
      const ushort_t* gb = Bt + (size_t)(n0 + row) * Kd + k0 + lk;
      __builtin_amdgcn_global_load_lds(
          (const __attribute__((address_space(1))) void*)ga,
          (__attribute__((address_space(3))) void*)(&As[b][0] + ch * 512), 16, 0, 0);
      __builtin_amdgcn_global_load_lds(
          (const __attribute__((address_space(1))) void*)gb,
          (__attribute__((address_space(3))) void*)(&Bs[b][0] + ch * 512), 16, 0, 0);
    }
  };

  const int nt = Kd / 32;
  STAGE(0, 0);
  STAGE(1, 32);

  int cur = 0;
  for (int t = 0; t < nt; ++t) {
    if (t + 1 < nt) {
      asm volatile("s_waitcnt vmcnt(4)" ::: "memory");
    } else {
      asm volatile("s_waitcnt vmcnt(0)" ::: "memory");
    }
    __builtin_amdgcn_s_barrier();
    if (t + 2 < nt) {
      int sb = cur + 2; if (sb >= 3) sb -= 3;
      STAGE(sb, (t + 2) * 32);
    }

    bf16x8 av[4], bv[4];
    #pragma unroll
    for (int mi = 0; mi < 4; ++mi)
      av[mi] = *reinterpret_cast<const bf16x8*>(&As[cur][0] + (wm * 64 + mi * 16 + fr) * 32 + kg);
    #pragma unroll
    for (int nj = 0; nj < 4; ++nj)
      bv[nj] = *reinterpret_cast<const bf16x8*>(&Bs[cur][0] + (wn * 64 + nj * 16 + fr) * 32 + kg);
    #pragma unroll
    for (int mi = 0; mi < 4; ++mi)
      #pragma unroll
      for (int nj = 0; nj < 4; ++nj)
        acc[mi][nj] = __builtin_amdgcn_mfma_f32_16x16x32_bf16(av[mi], bv[nj], acc[mi][nj], 0, 0, 0);

    cur = (cur == 2) ? 0 : cur + 1;
  }

  #pragma unroll
  for (int mi = 0; mi < 4; ++mi) {
    #pragma unroll
    for (int nj = 0; nj < 4; ++nj) {
      int rbase = m0 + wm * 64 + mi * 16 + (lane >> 4) * 4;
      int col   = n0 + wn * 64 + nj * 16 + fr;
      #pragma unroll
      for (int r = 0; r < 4; ++r) {
        int gr = rbase + r;
        if (gr < M) C[(size_t)gr * N + col] = acc[mi][nj][r];
      }
    }
  }
}

// ======================= MFMA flash attention (exp2 domain) ==================
__global__ __launch_bounds__(256)
void k_attn_mfma(const ushort_t* __restrict__ qb, const ushort_t* __restrict__ kb,
                 const ushort_t* __restrict__ vt, ushort_t* __restrict__ oattb)
{
  __shared__ __align__(16) ushort_t Ks[64 * 128];
  __shared__ __align__(16) ushort_t Vs[128 * 64];
  __shared__ __align__(16) ushort_t Ps[4][16 * 64];

  const int tid  = threadIdx.x;
  const int lane = tid & 63;
  const int w    = tid >> 6;
  const int l15  = lane & 15;
  const int g4   = lane >> 4;
  const int gh   = blockIdx.x;
  const int g = gh >> 4, h = gh & 15, kvh = (gh & 15) >> 2;
  const int qt = 15 - blockIdx.y;
  const int t0 = qt * 64;

  bf16x8 av[4];
  {
    int t = t0 + w * 16 + l15;
    const ushort_t* qrow = qb + (((size_t)(g * SQ + t)) * 16 + h) * 128;
    #pragma unroll
    for (int kk = 0; kk < 4; ++kk)
      av[kk] = *reinterpret_cast<const bf16x8*>(qrow + kk * 32 + g4 * 8);
  }

  bf16x8 ones;
  #pragma unroll
  for (int j = 0; j < 8; ++j) ones[j] = __builtin_bit_cast(__bf16, (ushort_t)0x3F80);

  f32x4 acc[8];
  #pragma unroll
  for (int dt = 0; dt < 8; ++dt) acc[dt] = (f32x4){0.f, 0.f, 0.f, 0.f};
  f32x4 acc_l = (f32x4){0.f, 0.f, 0.f, 0.f};
  float m[4];
  #pragma unroll
  for (int r = 0; r < 4; ++r) m[r] = -1e30f;

  ushort_t* pw = &Ps[w][0];

  for (int jt = 0; jt <= qt; ++jt) {
    int u0 = jt * 64;
    #pragma unroll
    for (int i = 0; i < 4; ++i) {
      int c = (w * 4 + i) * 64 + lane;
      int kv = c >> 4, sl = c & 15;
      const ushort_t* srck = kb + (size_t)(u0 + kv) * 512 + kvh * 128 + ((sl ^ (kv & 7)) << 3);
      __builtin_amdgcn_global_load_lds(
          (const __attribute__((address_space(1))) void*)srck,
          (__attribute__((address_space(3))) void*)(Ks + (w * 4 + i) * 512), 16, 0, 0);
      int d = c >> 3, sv = c & 7;
      const ushort_t* srcv = vt + (size_t)(kvh * 128 + d) * 1024 + u0 + ((sv ^ (d & 7)) << 3);
      __builtin_amdgcn_global_load_lds(
          (const __attribute__((address_space(1))) void*)srcv,
          (__attribute__((address_space(3))) void*)(Vs + (w * 4 + i) * 512), 16, 0, 0);
    }
    __syncthreads();

    f32x4 S[4];
    #pragma unroll
    for (int ct = 0; ct < 4; ++ct) S[ct] = (f32x4){0.f, 0.f, 0.f, 0.f};
    #pragma unroll
    for (int ct = 0; ct < 4; ++ct) {
      int kv = ct * 16 + l15;
      #pragma unroll
      for (int kk = 0; kk < 4; ++kk) {
        bf16x8 bv = *reinterpret_cast<const bf16x8*>(
            Ks + kv * 128 + ((((kk << 2) | g4) ^ (kv & 7)) << 3));
        S[ct] = __builtin_amdgcn_mfma_f32_16x16x32_bf16(av[kk], bv, S[ct], 0, 0, 0);
      }
    }
    if (jt == qt) {
      #pragma unroll
      for (int ct = 0; ct < 4; ++ct) {
        int u = u0 + ct * 16 + l15;
        #pragma unroll
        for (int r = 0; r < 4; ++r) {
          int t = t0 + w * 16 + g4 * 4 + r;
          if (u > t) S[ct][r] = -1e30f;
        }
      }
    }
    float tm[4];
    #pragma unroll
    for (int r = 0; r < 4; ++r) {
      float t1 = fmaxf(fmaxf(S[0][r], S[1][r]), fmaxf(S[2][r], S[3][r]));
      t1 = fmaxf(t1, __shfl_xor(t1, 1));
      t1 = fmaxf(t1, __shfl_xor(t1, 2));
      t1 = fmaxf(t1, __shfl_xor(t1, 4));
      t1 = fmaxf(t1, __shfl_xor(t1, 8));
      tm[r] = t1;
    }
    bool need = (tm[0] > m[0] + 8.f) || (tm[1] > m[1] + 8.f) ||
                (tm[2] > m[2] + 8.f) || (tm[3] > m[3] + 8.f);
    if (__any(need)) {
      #pragma unroll
      for (int r = 0; r < 4; ++r) {
        float mn = fmaxf(m[r], tm[r]);
        float corr = fexp2(m[r] - mn);
        m[r] = mn;
        acc_l[r] *= corr;
        #pragma unroll
        for (int dt = 0; dt < 8; ++dt) acc[dt][r] *= corr;
      }
    }
    #pragma unroll
    for (int r = 0; r < 4; ++r) {
      float e0 = S[0][r] - m[r];
      float e1 = S[1][r] - m[r];
      float e2 = S[2][r] - m[r];
      float e3 = S[3][r] - m[r];
      fexp2x4(e0, e1, e2, e3);
      S[0][r] = e0; S[1][r] = e1; S[2][r] = e2; S[3][r] = e3;
    }

    #pragma unroll
    for (int ct = 0; ct < 4; ++ct) {
      int kv = ct * 16 + l15;
      #pragma unroll
      for (int r = 0; r < 4; ++r) {
        int q = g4 * 4 + r;
        pw[q * 64 + ((((kv >> 3) ^ (q & 7)) << 3) | (kv & 7))] = f2bf_fast(S[ct][r]);
      }
    }
    #pragma unroll
    for (int kk = 0; kk < 2; ++kk) {
      bf16x8 pa = *reinterpret_cast<const bf16x8*>(
          pw + l15 * 64 + ((((kk << 2) | g4) ^ (l15 & 7)) << 3));
      acc_l = __builtin_amdgcn_mfma_f32_16x16x32_bf16(pa, ones, acc_l, 0, 0, 0);
      #pragma unroll
      for (int dt = 0; dt < 8; ++dt) {
        int d = dt * 16 + l15;
        bf16x8 vv = *reinterpret_cast<const bf16x8*>(
            Vs + d * 64 + ((((kk << 2) | g4) ^ (d & 7)) << 3));
        acc[dt] = __builtin_amdgcn_mfma_f32_16x16x32_bf16(pa, vv, acc[dt], 0, 0, 0);
      }
    }
    __syncthreads();
  }

  #pragma unroll
  for (int r = 0; r < 4; ++r) {
    int t = t0 + w * 16 + g4 * 4 + r;
    if (t >= SQ) continue;
    float inv = 1.f / acc_l[r];
    ushort_t* dst = oattb + ((size_t)(g * SQ + t)) * 2048 + h * 128;
    #pragma unroll
    for (int dt = 0; dt < 8; ++dt)
      dst[dt * 16 + l15] = f2bf_fast(acc[dt][r] * inv);
  }
}

// ======================= launch =======================
extern "C" void kernel_launch(void* const* d_in, const int* in_sizes, int n_in,
                              void* d_out, int out_size, void* d_ws, size_t ws_size,
                              hipStream_t stream) {
  const float* hidden = (const float*)d_in[0];   // (1024, 2048)
  const float* prevh  = (const float*)d_in[1];   // (1023, 2048)
  const float* Wq     = (const float*)d_in[4];   // (2048, 10240)
  const float* Wkv    = (const float*)d_in[5];   // (4096, 1024)
  const float* Wo     = (const float*)d_in[6];   // (2048, 2048)
  float* out = (float*)d_out;                    // (5115, 2048)

  char* ws = (char*)d_ws;
  float*    kvp   = (float*)ws;                        ws += (size_t)4 * SQ * 1024 * 4;
  float*    cosT  = (float*)ws;                        ws += (size_t)65472 * 4;
  float*    sinT  = (float*)ws;                        ws += (size_t)65472 * 4;
  ushort_t* qbb   = (ushort_t*)ws;                     ws += (size_t)5120 * 2048 * 2;
  ushort_t* kb    = (ushort_t*)ws;                     ws += (size_t)1024 * 512 * 2;
  ushort_t* vtb   = (ushort_t*)ws;                     ws += (size_t)512 * 1024 * 2;
  ushort_t* hbf   = (ushort_t*)ws;                     ws += (size_t)1024 * 2048 * 2;
  ushort_t* akv   = (ushort_t*)ws;                     ws += (size_t)1024 * 4096 * 2;
  ushort_t* oattb = (ushort_t*)ws;                     ws += (size_t)5120 * 2048 * 2;
  ushort_t* wqt   = (ushort_t*)ws;                     ws += (size_t)10240 * 2048 * 2;
  ushort_t* wkvt  = (ushort_t*)ws;                     ws += (size_t)1024 * 4096 * 2;
  ushort_t* wot   = (ushort_t*)ws;                     ws += (size_t)2048 * 2048 * 2;

  // 1. all preprocessing in one dispatch (tconv x3 + prep + tables)
  k_pre<<<dim3(20480 + 4096 + 4096 + 2046 + 256), dim3(256), 0, stream>>>(
      Wq, Wkv, Wo, hidden, prevh, wqt, wkvt, wot, hbf, akv, cosT, sinT);

  // 2. GEMM1(+RoPE) and GEMM2 co-scheduled (640 + 512 = 1152 blocks)
  k_gemms<<<dim3(1152), dim3(256), 0, stream>>>(
      hbf, wqt, qbb, cosT, sinT, akv, wkvt, kvp);

  // 3. K rope + V transpose (fold 4 kv partials), one dispatch
  k_kv<<<dim3(1023 + 512), dim3(256), 0, stream>>>(kvp, kb, vtb, cosT, sinT);

  // 4. MFMA flash attention -> bf16 O
  k_attn_mfma<<<dim3(80, 16), dim3(256), 0, stream>>>(qbb, kb, vtb, oattb);

  // 5. out = O_att @ Wo
  k_gemm3buf<<<dim3(HIDC / 128, 40), dim3(256), 0, stream>>>(oattb, wot, out, 5115, HIDC, 2048);
}

// Round 12
// 240.301 us; speedup vs baseline: 1.1923x; 1.0221x over previous
//
#include <hip/hip_runtime.h>
#include <cstddef>
#include <cstdint>

#define SQ    1023
#define HIDC  2048
#define NQC   10240
#define NKVC  1024

typedef unsigned short ushort_t;
typedef __bf16 bf16x8 __attribute__((ext_vector_type(8)));
typedef float  f32x4  __attribute__((ext_vector_type(4)));

__device__ __forceinline__ ushort_t f2bf(float x) {
  union { float f; uint32_t u; } v; v.f = x;
  uint32_t r = v.u + 0x7fffu + ((v.u >> 16) & 1u);   // RNE
  return (ushort_t)(r >> 16);
}

__device__ __forceinline__ ushort_t f2bf_fast(float x) {
  __bf16 b = (__bf16)x;
  return __builtin_bit_cast(ushort_t, b);
}

// raw v_exp_f32 (computes 2^x)
__device__ __forceinline__ float fexp2(float x) {
  float r;
  asm("v_exp_f32 %0, %1\n\ts_nop 0" : "=v"(r) : "v"(x));
  return r;
}

__device__ __forceinline__ void fexp2x4(float& a, float& b, float& c, float& d) {
  asm("v_exp_f32 %0, %0\n\t"
      "v_exp_f32 %1, %1\n\t"
      "v_exp_f32 %2, %2\n\t"
      "v_exp_f32 %3, %3\n\t"
      "s_nop 0"
      : "+v"(a), "+v"(b), "+v"(c), "+v"(d));
}

// ================= k_pre: tables U tconv(Wq,Wkv,Wo) U prep (one dispatch) ====
__device__ __forceinline__ void tconv_body(const float* __restrict__ in,
                                           ushort_t* __restrict__ out,
                                           int K, int N, int bx, int by,
                                           int tid, float (&t)[32][33]) {
  int n0 = bx * 32, k0 = by * 32;
  int r = tid >> 5, c = tid & 31;
  #pragma unroll
  for (int p = 0; p < 4; ++p)
    t[p * 8 + r][c] = in[(size_t)(k0 + p * 8 + r) * N + n0 + c];
  __syncthreads();
  #pragma unroll
  for (int p = 0; p < 4; ++p)
    out[(size_t)(n0 + p * 8 + r) * K + k0 + c] = f2bf(t[c][p * 8 + r]);
}

__global__ __launch_bounds__(256)
void k_pre(const float* __restrict__ Wq, const float* __restrict__ Wkv,
           const float* __restrict__ Wo, const float* __restrict__ hidden,
           const float* __restrict__ prevh,
           ushort_t* __restrict__ wqt, ushort_t* __restrict__ wkvt,
           ushort_t* __restrict__ wot, ushort_t* __restrict__ hbf,
           ushort_t* __restrict__ akv,
           float* __restrict__ cosT, float* __restrict__ sinT)
{
  __shared__ float tsh[32][33];
  const int tid = threadIdx.x;
  int b = blockIdx.x;
  if (b < 20480) { tconv_body(Wq, wqt, HIDC, NQC, b % 320, b / 320, tid, tsh); return; }
  b -= 20480;
  if (b < 4096)  { tconv_body(Wkv, wkvt, 4096, NKVC, b % 32, b / 32, tid, tsh); return; }
  b -= 4096;
  if (b < 4096)  { tconv_body(Wo, wot, HIDC, HIDC, b % 64, b / 64, tid, tsh); return; }
  b -= 4096;
  if (b < 2046) {
    int i = (b * 256 + tid) * 4;
    if (i >= SQ * 2048) return;
    int r = i >> 11, c = i & 2047;
    float4 h1 = *reinterpret_cast<const float4*>(hidden + (size_t)(r + 1) * 2048 + c);
    float4 h0 = *reinterpret_cast<const float4*>(hidden + (size_t)r * 2048 + c);
    float4 pv = *reinterpret_cast<const float4*>(prevh + (size_t)r * 2048 + c);
    uint2 a, bb, d;
    a.x  = (uint32_t)f2bf(h1.x) | ((uint32_t)f2bf(h1.y) << 16);
    a.y  = (uint32_t)f2bf(h1.z) | ((uint32_t)f2bf(h1.w) << 16);
    bb.x = (uint32_t)f2bf(pv.x) | ((uint32_t)f2bf(pv.y) << 16);
    bb.y = (uint32_t)f2bf(pv.z) | ((uint32_t)f2bf(pv.w) << 16);
    d.x  = (uint32_t)f2bf(h0.x) | ((uint32_t)f2bf(h0.y) << 16);
    d.y  = (uint32_t)f2bf(h0.z) | ((uint32_t)f2bf(h0.w) << 16);
    *reinterpret_cast<uint2*>(hbf + i) = a;
    *reinterpret_cast<uint2*>(akv + (size_t)r * 4096 + c) = bb;
    *reinterpret_cast<uint2*>(akv + (size_t)r * 4096 + 2048 + c) = d;
    return;
  }
  b -= 2046;
  {
    int idx = b * 256 + tid;
    if (idx >= SQ * 64) return;
    int t = idx >> 6, i = idx & 63;
    float inv = powf(10000.0f, -(float)i * (1.0f / 64.0f));
    float f = (float)t * inv;
    cosT[idx] = cosf(f);
    sinT[idx] = sinf(f);
  }
}

// ======== k_gemms: GEMM1+RoPE (blocks 0-639) U GEMM2 split-K (640-1151) ======
__global__ __launch_bounds__(256)
void k_gemms(const ushort_t* __restrict__ hbf, const ushort_t* __restrict__ wqt,
             ushort_t* __restrict__ qbb, const float* __restrict__ cosT,
             const float* __restrict__ sinT,
             const ushort_t* __restrict__ akv, const ushort_t* __restrict__ wkvt,
             float* __restrict__ kvp)
{
  __shared__ __align__(16) ushort_t As[3][128 * 32];
  __shared__ __align__(16) ushort_t Bs[3][128 * 32];

  const int tid  = threadIdx.x;
  const int lane = tid & 63;
  const int w    = tid >> 6;
  const int wm   = w >> 1, wn = w & 1;
  const int fr   = lane & 15;
  const int kg   = (lane >> 4) * 8;
  const int g4   = lane >> 4;
  const int lrow = lane >> 2;
  const int lk   = (lane & 3) * 8;

  if (blockIdx.x < 640) {
    const int Kd = 2048;
    const int m0 = (blockIdx.x / 80) * 128, n0 = (blockIdx.x % 80) * 128;
    const ushort_t* A  = hbf;
    const ushort_t* Bt = wqt;

    f32x4 acc[4][4];
    #pragma unroll
    for (int i = 0; i < 4; ++i)
      #pragma unroll
      for (int j = 0; j < 4; ++j) acc[i][j] = (f32x4){0.f, 0.f, 0.f, 0.f};

    auto STAGE = [&](int b, int k0) {
      #pragma unroll
      for (int c = 0; c < 2; ++c) {
        int ch  = w + c * 4;
        int row = ch * 16 + lrow;
        const ushort_t* ga = A  + (size_t)(m0 + row) * Kd + k0 + lk;
        const ushort_t* gb = Bt + (size_t)(n0 + row) * Kd + k0 + lk;
        __builtin_amdgcn_global_load_lds(
            (const __attribute__((address_space(1))) void*)ga,
            (__attribute__((address_space(3))) void*)(&As[b][0] + ch * 512), 16, 0, 0);
        __builtin_amdgcn_global_load_lds(
            (const __attribute__((address_space(1))) void*)gb,
            (__attribute__((address_space(3))) void*)(&Bs[b][0] + ch * 512), 16, 0, 0);
      }
    };

    const int nt = Kd / 32;
    STAGE(0, 0);
    STAGE(1, 32);

    int cur = 0;
    for (int t = 0; t < nt; ++t) {
      if (t + 1 < nt) {
        asm volatile("s_waitcnt vmcnt(4)" ::: "memory");
      } else {
        asm volatile("s_waitcnt vmcnt(0)" ::: "memory");
      }
      __builtin_amdgcn_s_barrier();
      if (t + 2 < nt) {
        int sb = cur + 2; if (sb >= 3) sb -= 3;
        STAGE(sb, (t + 2) * 32);
      }

      bf16x8 av[4], bv[4];
      #pragma unroll
      for (int mi = 0; mi < 4; ++mi)
        av[mi] = *reinterpret_cast<const bf16x8*>(&As[cur][0] + (wm * 64 + mi * 16 + fr) * 32 + kg);
      #pragma unroll
      for (int nj = 0; nj < 4; ++nj) {
        int colOff = wn * 32 + (nj & 1) * 16 + (nj >> 1) * 64;   // remapped for RoPE pairing
        bv[nj] = *reinterpret_cast<const bf16x8*>(&Bs[cur][0] + (colOff + fr) * 32 + kg);
      }
      #pragma unroll
      for (int mi = 0; mi < 4; ++mi)
        #pragma unroll
        for (int nj = 0; nj < 4; ++nj)
          acc[mi][nj] = __builtin_amdgcn_mfma_f32_16x16x32_bf16(av[mi], bv[nj], acc[mi][nj], 0, 0, 0);

      cur = (cur == 2) ? 0 : cur + 1;
    }

    const float sc = 0.1275174485f;   // log2(e) / sqrt(128)
    const int nChunk = n0 >> 11;
    #pragma unroll
    for (int mi = 0; mi < 4; ++mi) {
      #pragma unroll
      for (int r = 0; r < 4; ++r) {
        int gr = m0 + wm * 64 + mi * 16 + g4 * 4 + r;
        if (gr >= SQ) continue;
        int st  = gr * 5 + nChunk;
        int tau = st % 1023;
        const float* ct  = cosT + tau * 64;
        const float* stb = sinT + tau * 64;
        #pragma unroll
        for (int njp = 0; njp < 2; ++njp) {
          int dd = wn * 32 + njp * 16 + fr;
          float c = ct[dd], s = stb[dd];
          float x0 = acc[mi][njp][r];
          float x1 = acc[mi][njp + 2][r];
          size_t base = (size_t)gr * 10240 + n0 + dd;
          qbb[base]      = f2bf_fast((x0 * c - x1 * s) * sc);
          qbb[base + 64] = f2bf_fast((x1 * c + x0 * s) * sc);
        }
      }
    }
  } else {
    // ---------------- GEMM2 64x128 split-K x4 ----
    const int u = blockIdx.x - 640;
    const int Kd = 4096, M = SQ, N = NKVC, kLen = 1024;
    const int n0 = (u & 7) * 128, m0 = ((u >> 3) & 15) * 64;
    const int kOff = (u >> 7) * kLen;
    float* C = kvp + (size_t)(u >> 7) * M * N;
    ushort_t* As64 = &As[0][0];
    ushort_t* Bs64 = &Bs[0][0];

    const int arow = tid >> 2, aslot = (tid & 3) * 8;
    const int l15 = lane & 15;

    f32x4 acc[2][4];
    #pragma unroll
    for (int i = 0; i < 2; ++i)
      #pragma unroll
      for (int j = 0; j < 4; ++j) acc[i][j] = (f32x4){0.f, 0.f, 0.f, 0.f};

    for (int k0 = kOff; k0 < kOff + kLen; k0 += 32) {
      {
        const ushort_t* ga = akv + (size_t)(m0 + arow) * Kd + k0 + aslot;
        __builtin_amdgcn_global_load_lds(
            (const __attribute__((address_space(1))) void*)ga,
            (__attribute__((address_space(3))) void*)(As64 + w * 512), 16, 0, 0);
      }
      #pragma unroll
      for (int c = 0; c < 2; ++c) {
        int uu = c * 256 + tid;
        const ushort_t* gb = wkvt + (size_t)(n0 + (uu >> 2)) * Kd + k0 + (uu & 3) * 8;
        __builtin_amdgcn_global_load_lds(
            (const __attribute__((address_space(1))) void*)gb,
            (__attribute__((address_space(3))) void*)(Bs64 + (c * 256 + w * 64) * 8), 16, 0, 0);
      }
      __syncthreads();

      bf16x8 av[2], bv[4];
      #pragma unroll
      for (int mi = 0; mi < 2; ++mi)
        av[mi] = *reinterpret_cast<const bf16x8*>(As64 + (wm * 32 + mi * 16 + fr) * 32 + kg);
      #pragma unroll
      for (int nj = 0; nj < 4; ++nj)
        bv[nj] = *reinterpret_cast<const bf16x8*>(Bs64 + (wn * 64 + nj * 16 + fr) * 32 + kg);
      #pragma unroll
      for (int mi = 0; mi < 2; ++mi)
        #pragma unroll
        for (int nj = 0; nj < 4; ++nj)
          acc[mi][nj] = __builtin_amdgcn_mfma_f32_16x16x32_bf16(av[mi], bv[nj], acc[mi][nj], 0, 0, 0);
      __syncthreads();
    }

    #pragma unroll
    for (int mi = 0; mi < 2; ++mi) {
      #pragma unroll
      for (int nj = 0; nj < 4; ++nj) {
        int rbase = m0 + wm * 32 + mi * 16 + g4 * 4;
        int col   = n0 + wn * 64 + nj * 16 + l15;
        #pragma unroll
        for (int r = 0; r < 4; ++r) {
          int gr = rbase + r;
          if (gr < M) C[(size_t)gr * N + col] = acc[mi][nj][r];
        }
      }
    }
  }
}

// ============ k_kv: rope_k (blocks 0-1022) U vtrans (blocks 1023-1534) =======
__global__ __launch_bounds__(256)
void k_kv(const float* __restrict__ kvp, ushort_t* __restrict__ kb,
          ushort_t* __restrict__ vt, const float* __restrict__ cosT,
          const float* __restrict__ sinT)
{
  __shared__ float tile[32][33];
  const int tid = threadIdx.x;
  int b = blockIdx.x;
  if (b < 1023) {
    int idx = b * 256 + tid;
    if (idx >= SQ * 4 * 64) return;
    int d   = idx & 63;
    int kvh = (idx >> 6) & 3;
    int t   = idx >> 8;
    size_t src = (size_t)t * 1024 + kvh * 128 + d;
    float x0 = 0.f, x1 = 0.f;
    #pragma unroll
    for (int z = 0; z < 4; ++z) {
      x0 += kvp[(size_t)z * (SQ * 1024) + src];
      x1 += kvp[(size_t)z * (SQ * 1024) + src + 64];
    }
    float c = cosT[t * 64 + d], s = sinT[t * 64 + d];
    size_t dst = (size_t)t * 512 + kvh * 128 + d;
    kb[dst]      = f2bf(x0 * c - x1 * s);
    kb[dst + 64] = f2bf(x1 * c + x0 * s);
    return;
  }
  b -= 1023;
  {
    int v0 = (b & 15) * 32;
    int t0 = (b >> 4) * 32;
    int r = tid >> 5, c = tid & 31;
    #pragma unroll
    for (int p = 0; p < 4; ++p) {
      int t = t0 + p * 8 + r;
      float s = 0.f;
      if (t < SQ) {
        size_t src = (size_t)t * 1024 + 512 + v0 + c;
        #pragma unroll
        for (int z = 0; z < 4; ++z) s += kvp[(size_t)z * (SQ * 1024) + src];
      }
      tile[p * 8 + r][c] = s;
    }
    __syncthreads();
    #pragma unroll
    for (int p = 0; p < 4; ++p) {
      int v = v0 + p * 8 + r;
      vt[(size_t)v * 1024 + t0 + c] = f2bf(tile[c][p * 8 + r]);
    }
  }
}

// == bf16 MFMA GEMM, 128x128 tile, BK=32, 3-buffer + counted vmcnt (GEMM3) ====
__global__ __launch_bounds__(256)
void k_gemm3buf(const ushort_t* __restrict__ A, const ushort_t* __restrict__ Bt,
                float* __restrict__ C, int M, int N, int Kd)
{
  __shared__ __align__(16) ushort_t As[3][128 * 32];
  __shared__ __align__(16) ushort_t Bs[3][128 * 32];

  const int tid  = threadIdx.x;
  const int lane = tid & 63;
  const int w    = tid >> 6;
  const int wm   = w >> 1, wn = w & 1;
  const int fr   = lane & 15;
  const int kg   = (lane >> 4) * 8;
  const int m0   = blockIdx.y * 128, n0 = blockIdx.x * 128;

  const int lrow = lane >> 2;
  const int lk   = (lane & 3) * 8;

  f32x4 acc[4][4];
  #pragma unroll
  for (int i = 0; i < 4; ++i)
    #pragma unroll
    for (int j = 0; j < 4; ++j) acc[i][j] = (f32x4){0.f, 0.f, 0.f, 0.f};

  auto STAGE = [&](int b, int k0) {
    #pragma unroll
    for (int c = 0; c < 2; ++c) {
      int ch  = w + c * 4;
      int row = ch * 16 + lrow;
      const ushort_t* ga = A  + (size_t)(m0 + row) * Kd + k0 + lk;
      const ushort_t* gb = Bt + (size_t)(n0 + row) * Kd + k0 + lk;
      __builtin_amdgcn_global_load_lds(
          (const __attribute__((address_space(1))) void*)ga,
          (__attribute__((address_space(3))) void*)(&As[b][0] + ch * 512), 16, 0, 0);
      __builtin_amdgcn_global_load_lds(
          (const __attribute__((address_space(1))) void*)gb,
          (__attribute__((address_space(3))) void*)(&Bs[b][0] + ch * 512), 16, 0, 0);
    }
  };

  const int nt = Kd / 32;
  STAGE(0, 0);
  STAGE(1, 32);

  int cur = 0;
  for (int t = 0; t < nt; ++t) {
    if (t + 1 < nt) {
      asm volatile("s_waitcnt vmcnt(4)" ::: "memory");
    } else {
      asm volatile("s_waitcnt vmcnt(0)" ::: "memory");
    }
    __builtin_amdgcn_s_barrier();
    if (t + 2 < nt) {
      int sb = cur + 2; if (sb >= 3) sb -= 3;
      STAGE(sb, (t + 2) * 32);
    }

    bf16x8 av[4], bv[4];
    #pragma unroll
    for (int mi = 0; mi < 4; ++mi)
      av[mi] = *reinterpret_cast<const bf16x8*>(&As[cur][0] + (wm * 64 + mi * 16 + fr) * 32 + kg);
    #pragma unroll
    for (int nj = 0; nj < 4; ++nj)
      bv[nj] = *reinterpret_cast<const bf16x8*>(&Bs[cur][0] + (wn * 64 + nj * 16 + fr) * 32 + kg);
    #pragma unroll
    for (int mi = 0; mi < 4; ++mi)
      #pragma unroll
      for (int nj = 0; nj < 4; ++nj)
        acc[mi][nj] = __builtin_amdgcn_mfma_f32_16x16x32_bf16(av[mi], bv[nj], acc[mi][nj], 0, 0, 0);

    cur = (cur == 2) ? 0 : cur + 1;
  }

  #pragma unroll
  for (int mi = 0; mi < 4; ++mi) {
    #pragma unroll
    for (int nj = 0; nj < 4; ++nj) {
      int rbase = m0 + wm * 64 + mi * 16 + (lane >> 4) * 4;
      int col   = n0 + wn * 64 + nj * 16 + fr;
      #pragma unroll
      for (int r = 0; r < 4; ++r) {
        int gr = rbase + r;
        if (gr < M) C[(size_t)gr * N + col] = acc[mi][nj][r];
      }
    }
  }
}

// ======================= MFMA flash attention (swapped-QK, exp2 domain) ======
// grid (80, 16): x = g*16+h, y -> qt = 15 - y. 256 thr = 4 waves.
// S^T = mfma(K, Q): lane holds S^T[kv = ct*16+g4*4+r][q = l15] -> row-softmax
// is in-lane (tree) + 2 shfl. P stored [16 q][64 kv] bf16 via 4 ds_write_b64,
// PV = mfma(V, P): acc[dt][r] = O[q = l15][d = dt*16 + g4*4 + r].
__global__ __launch_bounds__(256)
void k_attn_mfma(const ushort_t* __restrict__ qb, const ushort_t* __restrict__ kb,
                 const ushort_t* __restrict__ vt, ushort_t* __restrict__ oattb)
{
  __shared__ __align__(16) ushort_t Ks[64 * 128];
  __shared__ __align__(16) ushort_t Vs[128 * 64];
  __shared__ __align__(16) ushort_t Ps[4][16 * 64]; // per-wave P [16 q][64 kv], XOR-swz

  const int tid  = threadIdx.x;
  const int lane = tid & 63;
  const int w    = tid >> 6;
  const int l15  = lane & 15;
  const int g4   = lane >> 4;
  const int gh   = blockIdx.x;
  const int g = gh >> 4, h = gh & 15, kvh = (gh & 15) >> 2;
  const int qt = 15 - blockIdx.y;
  const int t0 = qt * 64;
  const int tq = t0 + w * 16 + l15;        // this lane's q row

  bf16x8 av[4];
  {
    const ushort_t* qrow = qb + (((size_t)(g * SQ + tq)) * 16 + h) * 128;
    #pragma unroll
    for (int kk = 0; kk < 4; ++kk)
      av[kk] = *reinterpret_cast<const bf16x8*>(qrow + kk * 32 + g4 * 8);
  }

  f32x4 acc[8];
  #pragma unroll
  for (int dt = 0; dt < 8; ++dt) acc[dt] = (f32x4){0.f, 0.f, 0.f, 0.f};
  float lsum = 0.f;
  float m = -1e30f;

  char* pwb = (char*)&Ps[w][0] + l15 * 128;   // this lane's P row (bytes)
  const int pswz = (l15 & 7) << 4;            // byte XOR within row

  for (int jt = 0; jt <= qt; ++jt) {
    int u0 = jt * 64;
    #pragma unroll
    for (int i = 0; i < 4; ++i) {
      int c = (w * 4 + i) * 64 + lane;
      int kv = c >> 4, sl = c & 15;
      const ushort_t* srck = kb + (size_t)(u0 + kv) * 512 + kvh * 128 + ((sl ^ (kv & 7)) << 3);
      __builtin_amdgcn_global_load_lds(
          (const __attribute__((address_space(1))) void*)srck,
          (__attribute__((address_space(3))) void*)(Ks + (w * 4 + i) * 512), 16, 0, 0);
      int d = c >> 3, sv = c & 7;
      const ushort_t* srcv = vt + (size_t)(kvh * 128 + d) * 1024 + u0 + ((sv ^ (d & 7)) << 3);
      __builtin_amdgcn_global_load_lds(
          (const __attribute__((address_space(1))) void*)srcv,
          (__attribute__((address_space(3))) void*)(Vs + (w * 4 + i) * 512), 16, 0, 0);
    }
    __syncthreads();

    // S^T = K Q^T  (S[ct][r]: row kv = ct*16 + g4*4 + r, col q = l15)
    f32x4 S[4];
    #pragma unroll
    for (int ct = 0; ct < 4; ++ct) S[ct] = (f32x4){0.f, 0.f, 0.f, 0.f};
    #pragma unroll
    for (int ct = 0; ct < 4; ++ct) {
      int kv = ct * 16 + l15;
      #pragma unroll
      for (int kk = 0; kk < 4; ++kk) {
        bf16x8 kvf = *reinterpret_cast<const bf16x8*>(
            Ks + kv * 128 + ((((kk << 2) | g4) ^ (kv & 7)) << 3));
        S[ct] = __builtin_amdgcn_mfma_f32_16x16x32_bf16(kvf, av[kk], S[ct], 0, 0, 0);
      }
    }
    // causal mask: u = u0 + ct*16 + g4*4 + r vs t = tq
    if (jt == qt) {
      #pragma unroll
      for (int ct = 0; ct < 4; ++ct) {
        int ub = u0 + ct * 16 + g4 * 4;
        #pragma unroll
        for (int r = 0; r < 4; ++r)
          if (ub + r > tq) S[ct][r] = -1e30f;
      }
    }
    // in-lane max tree + 2 shfl (row q = l15 spread across g4 groups)
    float a0 = fmaxf(fmaxf(S[0][0], S[0][1]), fmaxf(S[0][2], S[0][3]));
    float a1 = fmaxf(fmaxf(S[1][0], S[1][1]), fmaxf(S[1][2], S[1][3]));
    float a2 = fmaxf(fmaxf(S[2][0], S[2][1]), fmaxf(S[2][2], S[2][3]));
    float a3 = fmaxf(fmaxf(S[3][0], S[3][1]), fmaxf(S[3][2], S[3][3]));
    float tm = fmaxf(fmaxf(a0, a1), fmaxf(a2, a3));
    tm = fmaxf(tm, __shfl_xor(tm, 16));
    tm = fmaxf(tm, __shfl_xor(tm, 32));

    // defer-max (T13, log2 units: P bounded by 2^8)
    bool need = tm > m + 8.f;
    if (__any(need)) {
      float mn = fmaxf(m, tm);
      float corr = fexp2(m - mn);
      m = mn;
      lsum *= corr;
      #pragma unroll
      for (int dt = 0; dt < 8; ++dt) acc[dt] *= corr;
    }

    // exp + pack + b64 store + partial sum, per ct
    float ps = 0.f;
    #pragma unroll
    for (int ct = 0; ct < 4; ++ct) {
      float e0 = S[ct][0] - m;
      float e1 = S[ct][1] - m;
      float e2 = S[ct][2] - m;
      float e3 = S[ct][3] - m;
      fexp2x4(e0, e1, e2, e3);
      ps += (e0 + e1) + (e2 + e3);
      uint2 pv;
      pv.x = (uint32_t)f2bf_fast(e0) | ((uint32_t)f2bf_fast(e1) << 16);
      pv.y = (uint32_t)f2bf_fast(e2) | ((uint32_t)f2bf_fast(e3) << 16);
      *reinterpret_cast<uint2*>(pwb + ((ct * 32 + g4 * 8) ^ pswz)) = pv;
    }
    ps += __shfl_xor(ps, 16);
    ps += __shfl_xor(ps, 32);
    lsum += ps;

    // O^T += V^T P^T : acc[dt] rows d = dt*16 + g4*4 + r, col q = l15
    #pragma unroll
    for (int kk = 0; kk < 2; ++kk) {
      bf16x8 pa = *reinterpret_cast<const bf16x8*>(pwb + ((kk * 64 + g4 * 16) ^ pswz));
      #pragma unroll
      for (int dt = 0; dt < 8; ++dt) {
        int d = dt * 16 + l15;
        bf16x8 vv = *reinterpret_cast<const bf16x8*>(
            Vs + d * 64 + ((((kk << 2) | g4) ^ (d & 7)) << 3));   // FIXED: (kk<<2)|g4
        acc[dt] = __builtin_amdgcn_mfma_f32_16x16x32_bf16(vv, pa, acc[dt], 0, 0, 0);
      }
    }
    __syncthreads();
  }

  // epilogue: lane writes O[tq][d = dt*16 + g4*4 + 0..3] as packed 8B
  if (tq < SQ) {
    float inv = 1.f / lsum;
    ushort_t* dst = oattb + ((size_t)(g * SQ + tq)) * 2048 + h * 128;
    #pragma unroll
    for (int dt = 0; dt < 8; ++dt) {
      uint2 ov;
      ov.x = (uint32_t)f2bf_fast(acc[dt][0] * inv) | ((uint32_t)f2bf_fast(acc[dt][1] * inv) << 16);
      ov.y = (uint32_t)f2bf_fast(acc[dt][2] * inv) | ((uint32_t)f2bf_fast(acc[dt][3] * inv) << 16);
      *reinterpret_cast<uint2*>(dst + dt * 16 + g4 * 4) = ov;
    }
  }
}

// ======================= launch =======================
extern "C" void kernel_launch(void* const* d_in, const int* in_sizes, int n_in,
                              void* d_out, int out_size, void* d_ws, size_t ws_size,
                              hipStream_t stream) {
  const float* hidden = (const float*)d_in[0];   // (1024, 2048)
  const float* prevh  = (const float*)d_in[1];   // (1023, 2048)
  const float* Wq     = (const float*)d_in[4];   // (2048, 10240)
  const float* Wkv    = (const float*)d_in[5];   // (4096, 1024)
  const float* Wo     = (const float*)d_in[6];   // (2048, 2048)
  float* out = (float*)d_out;                    // (5115, 2048)

  char* ws = (char*)d_ws;
  float*    kvp   = (float*)ws;                        ws += (size_t)4 * SQ * 1024 * 4;
  float*    cosT  = (float*)ws;                        ws += (size_t)65472 * 4;
  float*    sinT  = (float*)ws;                        ws += (size_t)65472 * 4;
  ushort_t* qbb   = (ushort_t*)ws;                     ws += (size_t)5120 * 2048 * 2;
  ushort_t* kb    = (ushort_t*)ws;                     ws += (size_t)1024 * 512 * 2;
  ushort_t* vtb   = (ushort_t*)ws;                     ws += (size_t)512 * 1024 * 2;
  ushort_t* hbf   = (ushort_t*)ws;                     ws += (size_t)1024 * 2048 * 2;
  ushort_t* akv   = (ushort_t*)ws;                     ws += (size_t)1024 * 4096 * 2;
  ushort_t* oattb = (ushort_t*)ws;                     ws += (size_t)5120 * 2048 * 2;
  ushort_t* wqt   = (ushort_t*)ws;                     ws += (size_t)10240 * 2048 * 2;
  ushort_t* wkvt  = (ushort_t*)ws;                     ws += (size_t)1024 * 4096 * 2;
  ushort_t* wot   = (ushort_t*)ws;                     ws += (size_t)2048 * 2048 * 2;

  // 1. all preprocessing in one dispatch (tconv x3 + prep + tables)
  k_pre<<<dim3(20480 + 4096 + 4096 + 2046 + 256), dim3(256), 0, stream>>>(
      Wq, Wkv, Wo, hidden, prevh, wqt, wkvt, wot, hbf, akv, cosT, sinT);

  // 2. GEMM1(+RoPE) and GEMM2 co-scheduled (640 + 512 = 1152 blocks)
  k_gemms<<<dim3(1152), dim3(256), 0, stream>>>(
      hbf, wqt, qbb, cosT, sinT, akv, wkvt, kvp);

  // 3. K rope + V transpose (fold 4 kv partials), one dispatch
  k_kv<<<dim3(1023 + 512), dim3(256), 0, stream>>>(kvp, kb, vtb, cosT, sinT);

  // 4. MFMA flash attention (swapped-QK) -> bf16 O
  k_attn_mfma<<<dim3(80, 16), dim3(256), 0, stream>>>(qbb, kb, vtb, oattb);

  // 5. out = O_att @ Wo
  k_gemm3buf<<<dim3(HIDC / 128, 40), dim3(256), 0, stream>>>(oattb, wot, out, 5115, HIDC, 2048);
}